// Round 6
// baseline (433.426 us; speedup 1.0000x reference)
//
#include <hip/hip_runtime.h>
#include <hip/hip_bf16.h>

#define N_NODES 50000
#define DIM 256
#define N_EDGES 1600000
#define NBUK 196            // buckets of 256 nodes: 196*256 = 50176 >= 50000
#define CHUNK_E 4096        // edges per binning block
#define NBLK ((N_EDGES + CHUNK_E - 1) / CHUNK_E)   // 391
#define NCHUNK 8            // Y column chunks (32 cols each), one per XCD
#define AGG_BPC 782         // aggregate blocks per chunk (2 groups per wave)
#define NGROUP (N_NODES / 8)   // 6250 groups of 8 nodes

typedef float f32x4 __attribute__((ext_vector_type(4)));
typedef __bf16 bf16x8 __attribute__((ext_vector_type(8)));
typedef __bf16 bf16x4 __attribute__((ext_vector_type(4)));
typedef unsigned long long u64;
typedef unsigned int u32;

// ---------------- W -> bf16 ----------------
__global__ void convw_k(const float* __restrict__ W, __bf16* __restrict__ Wbf) {
    int i = blockIdx.x * blockDim.x + threadIdx.x;
    if (i < DIM * DIM) Wbf[i] = (__bf16)W[i];
}

// ---------------- Y = feature @ W.T  (bf16 MFMA, no LDS) ----------------
// Output layout: Yc[chunk][node][32] with chunk = col>>5  (chunk-major, 3.2MB/chunk)
__global__ __launch_bounds__(256) void gemm_y(const float* __restrict__ feat,
                                              const __bf16* __restrict__ Wbf,
                                              __bf16* __restrict__ Yc) {
    const int wid  = threadIdx.x >> 6;
    const int lane = threadIdx.x & 63;
    const int row0 = blockIdx.x * 64 + wid * 16;
    const int mrow = lane & 15;
    const int kgrp = lane >> 4;          // 0..3

    int arow = row0 + mrow;
    int arow_c = arow < N_NODES ? arow : (N_NODES - 1);
    const float* aptr = feat + (size_t)arow_c * DIM + kgrp * 8;

    f32x4 acc[16];
#pragma unroll
    for (int i = 0; i < 16; ++i) acc[i] = (f32x4)0.0f;

#pragma unroll
    for (int ks = 0; ks < 8; ++ks) {
        const float* ap = aptr + ks * 32;
        f32x4 a0 = *(const f32x4*)(ap);
        f32x4 a1 = *(const f32x4*)(ap + 4);
        bf16x8 af;
        af[0] = (__bf16)a0[0]; af[1] = (__bf16)a0[1];
        af[2] = (__bf16)a0[2]; af[3] = (__bf16)a0[3];
        af[4] = (__bf16)a1[0]; af[5] = (__bf16)a1[1];
        af[6] = (__bf16)a1[2]; af[7] = (__bf16)a1[3];
#pragma unroll
        for (int nt = 0; nt < 16; ++nt) {
            int ncol = nt * 16 + mrow;   // B col for this lane
            const bf16x8 bf = *(const bf16x8*)(Wbf + (size_t)ncol * DIM + ks * 32 + kgrp * 8);
            acc[nt] = __builtin_amdgcn_mfma_f32_16x16x32_bf16(af, bf, acc[nt], 0, 0, 0);
        }
    }

    // C/D layout (m89): col = lane&15 (mrow), row = (lane>>4)*4 + reg
    int crow_base = row0 + kgrp * 4;
#pragma unroll
    for (int r = 0; r < 4; ++r) {
        int crow = crow_base + r;
        if (crow < N_NODES) {
#pragma unroll
            for (int nt = 0; nt < 16; ++nt) {
                // col = nt*16 + mrow -> chunk = nt>>1, within-chunk col = (nt&1)*16 + mrow
                __bf16* yp = Yc + (size_t)(nt >> 1) * N_NODES * 32
                               + (size_t)crow * 32 + (nt & 1) * 16 + mrow;
                *yp = (__bf16)acc[nt][r];
            }
        }
    }
}

// ---------------- bucket counts: per-block LDS hist, then aggregated atomics ----
__global__ __launch_bounds__(256) void count_k(const int* __restrict__ dst,
                                               int* __restrict__ gbkt) {
    __shared__ int lh[NBUK];
    for (int i = threadIdx.x; i < NBUK; i += 256) lh[i] = 0;
    __syncthreads();
    int base = blockIdx.x * CHUNK_E;
    int end = base + CHUNK_E; if (end > N_EDGES) end = N_EDGES;
    for (int e = base + threadIdx.x; e < end; e += 256)
        atomicAdd(&lh[dst[e] >> 8], 1);
    __syncthreads();
    for (int i = threadIdx.x; i < NBUK; i += 256)
        if (lh[i]) atomicAdd(&gbkt[i], lh[i]);
}

// ---------------- exclusive scan of 196 bucket totals ----------------
__global__ __launch_bounds__(256) void scanB_k(const int* __restrict__ gbkt,
                                               int* __restrict__ bbase,
                                               int* __restrict__ bcur,
                                               int* __restrict__ offsets) {
    __shared__ int sm[256];
    int t = threadIdx.x;
    int v = (t < NBUK) ? gbkt[t] : 0;
    sm[t] = v;
    __syncthreads();
    for (int off = 1; off < 256; off <<= 1) {
        int x = (t >= off) ? sm[t - off] : 0;
        __syncthreads();
        sm[t] += x;
        __syncthreads();
    }
    int excl = sm[t] - v;
    if (t < NBUK) { bbase[t] = excl; bcur[t] = excl; }
    if (t == 0) offsets[N_NODES] = N_EDGES;
}

// ---------------- place edges into bucket regions (block-local binning) --------
__global__ __launch_bounds__(256) void place_k(const int* __restrict__ src,
                                               const int* __restrict__ dst,
                                               int* __restrict__ bcur,
                                               unsigned int* __restrict__ staged) {
    __shared__ int lh[NBUK];
    __shared__ int lbase[NBUK];
    for (int i = threadIdx.x; i < NBUK; i += 256) lh[i] = 0;
    __syncthreads();
    int base = blockIdx.x * CHUNK_E;
    int end = base + CHUNK_E; if (end > N_EDGES) end = N_EDGES;
    for (int e = base + threadIdx.x; e < end; e += 256)
        atomicAdd(&lh[dst[e] >> 8], 1);
    __syncthreads();
    for (int i = threadIdx.x; i < NBUK; i += 256) {
        int c = lh[i];
        lbase[i] = c ? atomicAdd(&bcur[i], c) : 0;
        lh[i] = 0;                 // reuse as local cursor
    }
    __syncthreads();
    for (int e = base + threadIdx.x; e < end; e += 256) {
        int d = dst[e];
        int s = src[e];            // < 50000 -> fits in 16 bits
        int b = d >> 8;
        int p = atomicAdd(&lh[b], 1);
        staged[lbase[b] + p] = (unsigned int)s | ((unsigned int)(d & 255) << 16);
    }
}

// ---------------- per-bucket finalize: node offsets + CSR edge_src ----------------
__global__ __launch_bounds__(256) void finalize_k(const unsigned int* __restrict__ staged,
                                                  const int* __restrict__ bbase,
                                                  const int* __restrict__ gbkt,
                                                  int* __restrict__ offsets,
                                                  int* __restrict__ edge_src) {
    __shared__ int nh[256];
    __shared__ int nbase[256];
    __shared__ int sm[256];
    int t = threadIdx.x, b = blockIdx.x;
    int beg = bbase[b];
    int cnt = gbkt[b];
    nh[t] = 0;
    __syncthreads();
    for (int i = t; i < cnt; i += 256)
        atomicAdd(&nh[staged[beg + i] >> 16], 1);
    __syncthreads();
    int v = nh[t];
    sm[t] = v;
    __syncthreads();
    for (int off = 1; off < 256; off <<= 1) {
        int x = (t >= off) ? sm[t - off] : 0;
        __syncthreads();
        sm[t] += x;
        __syncthreads();
    }
    nbase[t] = sm[t] - v;
    int node = (b << 8) + t;
    if (node < N_NODES) offsets[node] = beg + nbase[t];
    nh[t] = 0;                     // reuse as per-node cursor
    __syncthreads();
    for (int i = t; i < cnt; i += 256) {
        unsigned int u = staged[beg + i];
        int dl = (int)(u >> 16);
        int p = atomicAdd(&nh[dl], 1);
        edge_src[beg + nbase[dl] + p] = (int)(u & 0xFFFFu);
    }
}

// ---------------- per-node gather-mean + bias, column-chunked, 8-deep pipeline --
// chunk = blockIdx & 7 (XCD round-robin); per-XCD working set = 3.2MB (L2-resident)
// wave = 8 nodes; segment (8 lanes) owns one node; lane covers 4 cols (8B/edge).
// Unroll 8 with clamped-index predication: 8 independent Y-loads in flight/lane.
// NT loads for edge stream + NT stores for out keep Yc resident in L2.
__global__ __launch_bounds__(256) void aggregate_k(const __bf16* __restrict__ Yc,
                                                   const int* __restrict__ offsets,
                                                   const int* __restrict__ edge_src,
                                                   const float* __restrict__ bias,
                                                   float* __restrict__ out) {
    const int chunk = blockIdx.x & 7;
    const int bic   = blockIdx.x >> 3;      // block index within chunk
    const int wid   = threadIdx.x >> 6;
    const int lane  = threadIdx.x & 63;
    const int seg   = lane >> 3;            // node slot 0..7
    const int cl    = (lane & 7) * 4;       // col within chunk (0,4,...,28)

    const __bf16* Ybase = Yc + (size_t)chunk * N_NODES * 32;
    const f32x4 bv = *(const f32x4*)(bias + chunk * 32 + cl);

    for (int g = bic * 4 + wid; g < NGROUP; g += AGG_BPC * 4) {
        const int node = g * 8 + seg;
        const int beg = offsets[node];
        const int end = offsets[node + 1];

        float a0 = 0.f, a1 = 0.f, a2 = 0.f, a3 = 0.f;
        for (int j = beg; j < end; j += 8) {
            int idx[8];
#pragma unroll
            for (int k = 0; k < 8; ++k) {
                int jj = j + k;
                jj = jj < end ? jj : end - 1;           // clamp (end>beg here)
                idx[k] = __builtin_nontemporal_load(edge_src + jj);
            }
            u64 q[8];
#pragma unroll
            for (int k = 0; k < 8; ++k)
                q[k] = __builtin_nontemporal_load(
                    (const u64*)(Ybase + (size_t)idx[k] * 32 + cl));
#pragma unroll
            for (int k = 0; k < 8; ++k) {
                u64 qq = (j + k < end) ? q[k] : 0ull;   // predicate tail edges to 0
                u32 lo = (u32)qq, hi = (u32)(qq >> 32);
                a0 += __uint_as_float(lo << 16);
                a1 += __uint_as_float(lo & 0xffff0000u);
                a2 += __uint_as_float(hi << 16);
                a3 += __uint_as_float(hi & 0xffff0000u);
            }
        }

        const int deg = end - beg;
        f32x4 r;
        if (deg > 0) {
            float inv = 1.0f / (float)deg;
            r[0] = a0 * inv + bv[0];
            r[1] = a1 * inv + bv[1];
            r[2] = a2 * inv + bv[2];
            r[3] = a3 * inv + bv[3];
        } else {
            bf16x4 v = *(const bf16x4*)(Ybase + (size_t)node * 32 + cl);
            r[0] = (float)v[0] + bv[0];
            r[1] = (float)v[1] + bv[1];
            r[2] = (float)v[2] + bv[2];
            r[3] = (float)v[3] + bv[3];
        }
        // all 64 lanes write: 8 segments x 128B contiguous f32 (NT: skip L2)
        __builtin_nontemporal_store(r, (f32x4*)(out + (size_t)node * DIM + chunk * 32 + cl));
    }
}

static inline size_t align64(size_t x) { return (x + 63) & ~(size_t)63; }

extern "C" void kernel_launch(void* const* d_in, const int* in_sizes, int n_in,
                              void* d_out, int out_size, void* d_ws, size_t ws_size,
                              hipStream_t stream) {
    const float* feature = (const float*)d_in[0];
    const int*   src     = (const int*)d_in[1];
    const int*   dst     = (const int*)d_in[2];
    const float* W       = (const float*)d_in[3];
    const float* b       = (const float*)d_in[4];
    float* out = (float*)d_out;

    // workspace layout (~38.8 MB total)
    char* ws = (char*)d_ws;
    __bf16* Yc  = (__bf16*)ws;               ws += align64((size_t)N_NODES * DIM * 2);
    __bf16* Wbf = (__bf16*)ws;               ws += align64((size_t)DIM * DIM * 2);
    int* offsets  = (int*)ws;                ws += align64((size_t)(N_NODES + 1) * 4);
    int* gbkt     = (int*)ws;                ws += align64((size_t)NBUK * 4);
    int* bbase    = (int*)ws;                ws += align64((size_t)NBUK * 4);
    int* bcur     = (int*)ws;                ws += align64((size_t)NBUK * 4);
    unsigned int* staged = (unsigned int*)ws; ws += align64((size_t)N_EDGES * 4);
    int* edge_src = (int*)ws;                ws += align64((size_t)N_EDGES * 4);

    hipMemsetAsync(gbkt, 0, (size_t)NBUK * 4, stream);

    convw_k<<<(DIM * DIM + 255) / 256, 256, 0, stream>>>(W, Wbf);
    gemm_y<<<(N_NODES + 63) / 64, 256, 0, stream>>>(feature, Wbf, Yc);
    count_k<<<NBLK, 256, 0, stream>>>(dst, gbkt);
    scanB_k<<<1, 256, 0, stream>>>(gbkt, bbase, bcur, offsets);
    place_k<<<NBLK, 256, 0, stream>>>(src, dst, bcur, staged);
    finalize_k<<<NBUK, 256, 0, stream>>>(staged, bbase, gbkt, offsets, edge_src);
    aggregate_k<<<NCHUNK * AGG_BPC, 256, 0, stream>>>(Yc, offsets, edge_src, b, out);
}

// Round 7
// 335.497 us; speedup vs baseline: 1.2919x; 1.2919x over previous
//
#include <hip/hip_runtime.h>
#include <hip/hip_bf16.h>

#define N_NODES 50000
#define DIM 256
#define N_EDGES 1600000
#define NBUK 196            // buckets of 256 nodes: 196*256 = 50176 >= 50000
#define CHUNK_E 4096        // edges per binning block
#define NBLK ((N_EDGES + CHUNK_E - 1) / CHUNK_E)   // 391
#define NCHUNK 8            // Y column chunks (32 cols each), one per XCD
#define AGG_BPC 782         // aggregate blocks per chunk (2 groups per wave)
#define NGROUP (N_NODES / 8)   // 6250 groups of 8 nodes

typedef float f32x4 __attribute__((ext_vector_type(4)));
typedef __bf16 bf16x8 __attribute__((ext_vector_type(8)));
typedef __bf16 bf16x4 __attribute__((ext_vector_type(4)));
typedef unsigned long long u64;
typedef unsigned int u32;

// ---------------- W -> bf16 ----------------
__global__ void convw_k(const float* __restrict__ W, __bf16* __restrict__ Wbf) {
    int i = blockIdx.x * blockDim.x + threadIdx.x;
    if (i < DIM * DIM) Wbf[i] = (__bf16)W[i];
}

// ---------------- Y = feature @ W.T  (bf16 MFMA, no LDS) ----------------
// Output layout: Yc[chunk][node][32] with chunk = col>>5  (chunk-major, 3.2MB/chunk)
__global__ __launch_bounds__(256) void gemm_y(const float* __restrict__ feat,
                                              const __bf16* __restrict__ Wbf,
                                              __bf16* __restrict__ Yc) {
    const int wid  = threadIdx.x >> 6;
    const int lane = threadIdx.x & 63;
    const int row0 = blockIdx.x * 64 + wid * 16;
    const int mrow = lane & 15;
    const int kgrp = lane >> 4;          // 0..3

    int arow = row0 + mrow;
    int arow_c = arow < N_NODES ? arow : (N_NODES - 1);
    const float* aptr = feat + (size_t)arow_c * DIM + kgrp * 8;

    f32x4 acc[16];
#pragma unroll
    for (int i = 0; i < 16; ++i) acc[i] = (f32x4)0.0f;

#pragma unroll
    for (int ks = 0; ks < 8; ++ks) {
        const float* ap = aptr + ks * 32;
        f32x4 a0 = *(const f32x4*)(ap);
        f32x4 a1 = *(const f32x4*)(ap + 4);
        bf16x8 af;
        af[0] = (__bf16)a0[0]; af[1] = (__bf16)a0[1];
        af[2] = (__bf16)a0[2]; af[3] = (__bf16)a0[3];
        af[4] = (__bf16)a1[0]; af[5] = (__bf16)a1[1];
        af[6] = (__bf16)a1[2]; af[7] = (__bf16)a1[3];
#pragma unroll
        for (int nt = 0; nt < 16; ++nt) {
            int ncol = nt * 16 + mrow;   // B col for this lane
            const bf16x8 bf = *(const bf16x8*)(Wbf + (size_t)ncol * DIM + ks * 32 + kgrp * 8);
            acc[nt] = __builtin_amdgcn_mfma_f32_16x16x32_bf16(af, bf, acc[nt], 0, 0, 0);
        }
    }

    // C/D layout (m89): col = lane&15 (mrow), row = (lane>>4)*4 + reg
    int crow_base = row0 + kgrp * 4;
#pragma unroll
    for (int r = 0; r < 4; ++r) {
        int crow = crow_base + r;
        if (crow < N_NODES) {
#pragma unroll
            for (int nt = 0; nt < 16; ++nt) {
                // col = nt*16 + mrow -> chunk = nt>>1, within-chunk col = (nt&1)*16 + mrow
                __bf16* yp = Yc + (size_t)(nt >> 1) * N_NODES * 32
                               + (size_t)crow * 32 + (nt & 1) * 16 + mrow;
                *yp = (__bf16)acc[nt][r];
            }
        }
    }
}

// ---------------- bucket counts: per-block LDS hist, then aggregated atomics ----
__global__ __launch_bounds__(256) void count_k(const int* __restrict__ dst,
                                               int* __restrict__ gbkt) {
    __shared__ int lh[NBUK];
    for (int i = threadIdx.x; i < NBUK; i += 256) lh[i] = 0;
    __syncthreads();
    int base = blockIdx.x * CHUNK_E;
    int end = base + CHUNK_E; if (end > N_EDGES) end = N_EDGES;
    for (int e = base + threadIdx.x; e < end; e += 256)
        atomicAdd(&lh[dst[e] >> 8], 1);
    __syncthreads();
    for (int i = threadIdx.x; i < NBUK; i += 256)
        if (lh[i]) atomicAdd(&gbkt[i], lh[i]);
}

// ---------------- exclusive scan of 196 bucket totals ----------------
__global__ __launch_bounds__(256) void scanB_k(const int* __restrict__ gbkt,
                                               int* __restrict__ bbase,
                                               int* __restrict__ bcur,
                                               int* __restrict__ offsets) {
    __shared__ int sm[256];
    int t = threadIdx.x;
    int v = (t < NBUK) ? gbkt[t] : 0;
    sm[t] = v;
    __syncthreads();
    for (int off = 1; off < 256; off <<= 1) {
        int x = (t >= off) ? sm[t - off] : 0;
        __syncthreads();
        sm[t] += x;
        __syncthreads();
    }
    int excl = sm[t] - v;
    if (t < NBUK) { bbase[t] = excl; bcur[t] = excl; }
    if (t == 0) offsets[N_NODES] = N_EDGES;
}

// ---------------- place edges into bucket regions (block-local binning) --------
__global__ __launch_bounds__(256) void place_k(const int* __restrict__ src,
                                               const int* __restrict__ dst,
                                               int* __restrict__ bcur,
                                               unsigned int* __restrict__ staged) {
    __shared__ int lh[NBUK];
    __shared__ int lbase[NBUK];
    for (int i = threadIdx.x; i < NBUK; i += 256) lh[i] = 0;
    __syncthreads();
    int base = blockIdx.x * CHUNK_E;
    int end = base + CHUNK_E; if (end > N_EDGES) end = N_EDGES;
    for (int e = base + threadIdx.x; e < end; e += 256)
        atomicAdd(&lh[dst[e] >> 8], 1);
    __syncthreads();
    for (int i = threadIdx.x; i < NBUK; i += 256) {
        int c = lh[i];
        lbase[i] = c ? atomicAdd(&bcur[i], c) : 0;
        lh[i] = 0;                 // reuse as local cursor
    }
    __syncthreads();
    for (int e = base + threadIdx.x; e < end; e += 256) {
        int d = dst[e];
        int s = src[e];            // < 50000 -> fits in 16 bits
        int b = d >> 8;
        int p = atomicAdd(&lh[b], 1);
        staged[lbase[b] + p] = (unsigned int)s | ((unsigned int)(d & 255) << 16);
    }
}

// ---------------- per-bucket finalize: node offsets + CSR edge_src ----------------
__global__ __launch_bounds__(256) void finalize_k(const unsigned int* __restrict__ staged,
                                                  const int* __restrict__ bbase,
                                                  const int* __restrict__ gbkt,
                                                  int* __restrict__ offsets,
                                                  int* __restrict__ edge_src) {
    __shared__ int nh[256];
    __shared__ int nbase[256];
    __shared__ int sm[256];
    int t = threadIdx.x, b = blockIdx.x;
    int beg = bbase[b];
    int cnt = gbkt[b];
    nh[t] = 0;
    __syncthreads();
    for (int i = t; i < cnt; i += 256)
        atomicAdd(&nh[staged[beg + i] >> 16], 1);
    __syncthreads();
    int v = nh[t];
    sm[t] = v;
    __syncthreads();
    for (int off = 1; off < 256; off <<= 1) {
        int x = (t >= off) ? sm[t - off] : 0;
        __syncthreads();
        sm[t] += x;
        __syncthreads();
    }
    nbase[t] = sm[t] - v;
    int node = (b << 8) + t;
    if (node < N_NODES) offsets[node] = beg + nbase[t];
    nh[t] = 0;                     // reuse as per-node cursor
    __syncthreads();
    for (int i = t; i < cnt; i += 256) {
        unsigned int u = staged[beg + i];
        int dl = (int)(u >> 16);
        int p = atomicAdd(&nh[dl], 1);
        edge_src[beg + nbase[dl] + p] = (int)(u & 0xFFFFu);
    }
}

// ---------------- per-node gather-mean + bias, column-chunked, 8-deep pipeline --
// chunk = blockIdx & 7 (XCD round-robin); per-XCD working set = 3.2MB (L2-resident)
// wave = 8 nodes; segment (8 lanes) owns one node; lane covers 4 cols (8B/edge).
// 8 independent CACHED Y-loads in flight/lane; NT only on the streaming
// edge_src reads and out writes (so they don't evict the Yc slice from L2).
__global__ __launch_bounds__(256) void aggregate_k(const __bf16* __restrict__ Yc,
                                                   const int* __restrict__ offsets,
                                                   const int* __restrict__ edge_src,
                                                   const float* __restrict__ bias,
                                                   float* __restrict__ out) {
    const int chunk = blockIdx.x & 7;
    const int bic   = blockIdx.x >> 3;      // block index within chunk
    const int wid   = threadIdx.x >> 6;
    const int lane  = threadIdx.x & 63;
    const int seg   = lane >> 3;            // node slot 0..7
    const int cl    = (lane & 7) * 4;       // col within chunk (0,4,...,28)

    const __bf16* Ybase = Yc + (size_t)chunk * N_NODES * 32;
    const f32x4 bv = *(const f32x4*)(bias + chunk * 32 + cl);

    for (int g = bic * 4 + wid; g < NGROUP; g += AGG_BPC * 4) {
        const int node = g * 8 + seg;
        const int beg = offsets[node];
        const int end = offsets[node + 1];

        float a0 = 0.f, a1 = 0.f, a2 = 0.f, a3 = 0.f;
        for (int j = beg; j < end; j += 8) {
            int idx[8];
#pragma unroll
            for (int k = 0; k < 8; ++k) {
                int jj = j + k;
                jj = jj < end ? jj : end - 1;           // clamp (end>beg here)
                idx[k] = __builtin_nontemporal_load(edge_src + jj);
            }
            u64 q[8];
#pragma unroll
            for (int k = 0; k < 8; ++k)
                q[k] = *(const u64*)(Ybase + (size_t)idx[k] * 32 + cl);  // cached!
#pragma unroll
            for (int k = 0; k < 8; ++k) {
                u64 qq = (j + k < end) ? q[k] : 0ull;   // predicate tail edges to 0
                u32 lo = (u32)qq, hi = (u32)(qq >> 32);
                a0 += __uint_as_float(lo << 16);
                a1 += __uint_as_float(lo & 0xffff0000u);
                a2 += __uint_as_float(hi << 16);
                a3 += __uint_as_float(hi & 0xffff0000u);
            }
        }

        const int deg = end - beg;
        f32x4 r;
        if (deg > 0) {
            float inv = 1.0f / (float)deg;
            r[0] = a0 * inv + bv[0];
            r[1] = a1 * inv + bv[1];
            r[2] = a2 * inv + bv[2];
            r[3] = a3 * inv + bv[3];
        } else {
            bf16x4 v = *(const bf16x4*)(Ybase + (size_t)node * 32 + cl);
            r[0] = (float)v[0] + bv[0];
            r[1] = (float)v[1] + bv[1];
            r[2] = (float)v[2] + bv[2];
            r[3] = (float)v[3] + bv[3];
        }
        // all 64 lanes write: 8 segments x 128B contiguous f32 (NT: skip L2)
        __builtin_nontemporal_store(r, (f32x4*)(out + (size_t)node * DIM + chunk * 32 + cl));
    }
}

static inline size_t align64(size_t x) { return (x + 63) & ~(size_t)63; }

extern "C" void kernel_launch(void* const* d_in, const int* in_sizes, int n_in,
                              void* d_out, int out_size, void* d_ws, size_t ws_size,
                              hipStream_t stream) {
    const float* feature = (const float*)d_in[0];
    const int*   src     = (const int*)d_in[1];
    const int*   dst     = (const int*)d_in[2];
    const float* W       = (const float*)d_in[3];
    const float* b       = (const float*)d_in[4];
    float* out = (float*)d_out;

    // workspace layout (~38.8 MB total)
    char* ws = (char*)d_ws;
    __bf16* Yc  = (__bf16*)ws;               ws += align64((size_t)N_NODES * DIM * 2);
    __bf16* Wbf = (__bf16*)ws;               ws += align64((size_t)DIM * DIM * 2);
    int* offsets  = (int*)ws;                ws += align64((size_t)(N_NODES + 1) * 4);
    int* gbkt     = (int*)ws;                ws += align64((size_t)NBUK * 4);
    int* bbase    = (int*)ws;                ws += align64((size_t)NBUK * 4);
    int* bcur     = (int*)ws;                ws += align64((size_t)NBUK * 4);
    unsigned int* staged = (unsigned int*)ws; ws += align64((size_t)N_EDGES * 4);
    int* edge_src = (int*)ws;                ws += align64((size_t)N_EDGES * 4);

    hipMemsetAsync(gbkt, 0, (size_t)NBUK * 4, stream);

    convw_k<<<(DIM * DIM + 255) / 256, 256, 0, stream>>>(W, Wbf);
    gemm_y<<<(N_NODES + 63) / 64, 256, 0, stream>>>(feature, Wbf, Yc);
    count_k<<<NBLK, 256, 0, stream>>>(dst, gbkt);
    scanB_k<<<1, 256, 0, stream>>>(gbkt, bbase, bcur, offsets);
    place_k<<<NBLK, 256, 0, stream>>>(src, dst, bcur, staged);
    finalize_k<<<NBUK, 256, 0, stream>>>(staged, bbase, gbkt, offsets, edge_src);
    aggregate_k<<<NCHUNK * AGG_BPC, 256, 0, stream>>>(Yc, offsets, edge_src, b, out);
}

// Round 8
// 241.626 us; speedup vs baseline: 1.7938x; 1.3885x over previous
//
#include <hip/hip_runtime.h>
#include <hip/hip_bf16.h>

#define N_NODES 50000
#define DIM 256
#define N_EDGES 1600000
#define NBUK 196            // buckets of 256 nodes: 196*256 = 50176 >= 50000
#define CHUNK_E 4096        // edges per binning block
#define NBLK ((N_EDGES + CHUNK_E - 1) / CHUNK_E)   // 391
#define NCHUNK 8            // Y column chunks (32 cols each), one per XCD
#define AGG_BPC 391         // aggregate blocks per chunk (~2 groups per wave)
#define NGROUP (N_NODES / 16)  // 3125 groups of 16 nodes

typedef float f32x4 __attribute__((ext_vector_type(4)));
typedef __bf16 bf16x8 __attribute__((ext_vector_type(8)));
typedef __bf16 bf16x4 __attribute__((ext_vector_type(4)));
typedef unsigned int u32;

// ---------------- W -> bf16 ----------------
__global__ void convw_k(const float* __restrict__ W, __bf16* __restrict__ Wbf) {
    int i = blockIdx.x * blockDim.x + threadIdx.x;
    if (i < DIM * DIM) Wbf[i] = (__bf16)W[i];
}

// ---------------- Y = feature @ W.T  (bf16 MFMA, swapped operands) ----------------
// mfma(W_frag, feat_frag, acc): D col(lane&15)=node, row((lane>>4)*4+reg)=outcol.
// Per lane, regs r=0..3 are 4 CONSECUTIVE outcols -> one 8B bf16x4 store per tile.
// Output layout: Yc[chunk][node][32] with chunk = outcol>>5 (chunk-major, 3.2MB/chunk)
__global__ __launch_bounds__(256) void gemm_y(const float* __restrict__ feat,
                                              const __bf16* __restrict__ Wbf,
                                              __bf16* __restrict__ Yc) {
    const int wid  = threadIdx.x >> 6;
    const int lane = threadIdx.x & 63;
    const int row0 = blockIdx.x * 64 + wid * 16;
    const int mrow = lane & 15;
    const int kgrp = lane >> 4;          // 0..3

    int arow = row0 + mrow;
    int arow_c = arow < N_NODES ? arow : (N_NODES - 1);
    const float* aptr = feat + (size_t)arow_c * DIM + kgrp * 8;

    f32x4 acc[16];
#pragma unroll
    for (int i = 0; i < 16; ++i) acc[i] = (f32x4)0.0f;

#pragma unroll
    for (int ks = 0; ks < 8; ++ks) {
        const float* ap = aptr + ks * 32;
        f32x4 a0 = *(const f32x4*)(ap);
        f32x4 a1 = *(const f32x4*)(ap + 4);
        bf16x8 af;                        // feat fragment: n-side after swap
        af[0] = (__bf16)a0[0]; af[1] = (__bf16)a0[1];
        af[2] = (__bf16)a0[2]; af[3] = (__bf16)a0[3];
        af[4] = (__bf16)a1[0]; af[5] = (__bf16)a1[1];
        af[6] = (__bf16)a1[2]; af[7] = (__bf16)a1[3];
#pragma unroll
        for (int nt = 0; nt < 16; ++nt) {
            int ncol = nt * 16 + mrow;   // W row (outcol) for this lane: m-side
            const bf16x8 wf = *(const bf16x8*)(Wbf + (size_t)ncol * DIM + ks * 32 + kgrp * 8);
            // SWAPPED: A = W (m=outcol), B = feat (n=node)
            acc[nt] = __builtin_amdgcn_mfma_f32_16x16x32_bf16(wf, af, acc[nt], 0, 0, 0);
        }
    }

    // D layout (m89): col = lane&15 = node, row = (lane>>4)*4 + r = outcol-in-tile
    const int node = row0 + mrow;
    if (node < N_NODES) {
#pragma unroll
        for (int nt = 0; nt < 16; ++nt) {
            int oc0 = nt * 16 + kgrp * 4;          // outcol of reg 0 (mod 4 == 0)
            bf16x4 pv;
            pv[0] = (__bf16)acc[nt][0];
            pv[1] = (__bf16)acc[nt][1];
            pv[2] = (__bf16)acc[nt][2];
            pv[3] = (__bf16)acc[nt][3];
            __bf16* yp = Yc + (size_t)(oc0 >> 5) * N_NODES * 32
                            + (size_t)node * 32 + (oc0 & 31);
            *(bf16x4*)yp = pv;                     // 8B store
        }
    }
}

// ---------------- bucket counts: per-block LDS hist, then aggregated atomics ----
__global__ __launch_bounds__(256) void count_k(const int* __restrict__ dst,
                                               int* __restrict__ gbkt) {
    __shared__ int lh[NBUK];
    for (int i = threadIdx.x; i < NBUK; i += 256) lh[i] = 0;
    __syncthreads();
    int base = blockIdx.x * CHUNK_E;
    int end = base + CHUNK_E; if (end > N_EDGES) end = N_EDGES;
    for (int e = base + threadIdx.x; e < end; e += 256)
        atomicAdd(&lh[dst[e] >> 8], 1);
    __syncthreads();
    for (int i = threadIdx.x; i < NBUK; i += 256)
        if (lh[i]) atomicAdd(&gbkt[i], lh[i]);
}

// ---------------- exclusive scan of 196 bucket totals ----------------
__global__ __launch_bounds__(256) void scanB_k(const int* __restrict__ gbkt,
                                               int* __restrict__ bbase,
                                               int* __restrict__ bcur,
                                               int* __restrict__ offsets) {
    __shared__ int sm[256];
    int t = threadIdx.x;
    int v = (t < NBUK) ? gbkt[t] : 0;
    sm[t] = v;
    __syncthreads();
    for (int off = 1; off < 256; off <<= 1) {
        int x = (t >= off) ? sm[t - off] : 0;
        __syncthreads();
        sm[t] += x;
        __syncthreads();
    }
    int excl = sm[t] - v;
    if (t < NBUK) { bbase[t] = excl; bcur[t] = excl; }
    if (t == 0) offsets[N_NODES] = N_EDGES;
}

// ---------------- place edges into bucket regions (block-local binning) --------
__global__ __launch_bounds__(256) void place_k(const int* __restrict__ src,
                                               const int* __restrict__ dst,
                                               int* __restrict__ bcur,
                                               unsigned int* __restrict__ staged) {
    __shared__ int lh[NBUK];
    __shared__ int lbase[NBUK];
    for (int i = threadIdx.x; i < NBUK; i += 256) lh[i] = 0;
    __syncthreads();
    int base = blockIdx.x * CHUNK_E;
    int end = base + CHUNK_E; if (end > N_EDGES) end = N_EDGES;
    for (int e = base + threadIdx.x; e < end; e += 256)
        atomicAdd(&lh[dst[e] >> 8], 1);
    __syncthreads();
    for (int i = threadIdx.x; i < NBUK; i += 256) {
        int c = lh[i];
        lbase[i] = c ? atomicAdd(&bcur[i], c) : 0;
        lh[i] = 0;                 // reuse as local cursor
    }
    __syncthreads();
    for (int e = base + threadIdx.x; e < end; e += 256) {
        int d = dst[e];
        int s = src[e];            // < 50000 -> fits in 16 bits
        int b = d >> 8;
        int p = atomicAdd(&lh[b], 1);
        staged[lbase[b] + p] = (unsigned int)s | ((unsigned int)(d & 255) << 16);
    }
}

// ---------------- per-bucket finalize: node offsets + CSR edge_src ----------------
__global__ __launch_bounds__(256) void finalize_k(const unsigned int* __restrict__ staged,
                                                  const int* __restrict__ bbase,
                                                  const int* __restrict__ gbkt,
                                                  int* __restrict__ offsets,
                                                  int* __restrict__ edge_src) {
    __shared__ int nh[256];
    __shared__ int nbase[256];
    __shared__ int sm[256];
    int t = threadIdx.x, b = blockIdx.x;
    int beg = bbase[b];
    int cnt = gbkt[b];
    nh[t] = 0;
    __syncthreads();
    for (int i = t; i < cnt; i += 256)
        atomicAdd(&nh[staged[beg + i] >> 16], 1);
    __syncthreads();
    int v = nh[t];
    sm[t] = v;
    __syncthreads();
    for (int off = 1; off < 256; off <<= 1) {
        int x = (t >= off) ? sm[t - off] : 0;
        __syncthreads();
        sm[t] += x;
        __syncthreads();
    }
    nbase[t] = sm[t] - v;
    int node = (b << 8) + t;
    if (node < N_NODES) offsets[node] = beg + nbase[t];
    nh[t] = 0;                     // reuse as per-node cursor
    __syncthreads();
    for (int i = t; i < cnt; i += 256) {
        unsigned int u = staged[beg + i];
        int dl = (int)(u >> 16);
        int p = atomicAdd(&nh[dl], 1);
        edge_src[beg + nbase[dl] + p] = (int)(u & 0xFFFFu);
    }
}

// ---------------- per-node gather-mean + bias, column-chunked, wide gather -----
// chunk = blockIdx & 7 (XCD round-robin); per-XCD working set = 3.2MB (L2-resident)
// wave = 16 nodes; segment (4 lanes) owns one node; lane covers 8 cols (16B/edge).
// 16 distinct 64B lines per Y-load instruction (2x R5). Cached loads, plain stores.
__global__ __launch_bounds__(256) void aggregate_k(const __bf16* __restrict__ Yc,
                                                   const int* __restrict__ offsets,
                                                   const int* __restrict__ edge_src,
                                                   const float* __restrict__ bias,
                                                   float* __restrict__ out) {
    const int chunk = blockIdx.x & 7;
    const int bic   = blockIdx.x >> 3;      // block index within chunk
    const int wid   = threadIdx.x >> 6;
    const int lane  = threadIdx.x & 63;
    const int seg   = lane >> 2;            // node slot 0..15
    const int cl    = (lane & 3) * 8;       // bf16 col within chunk: 0,8,16,24

    const __bf16* Ybase = Yc + (size_t)chunk * N_NODES * 32;
    const float* bp = bias + chunk * 32 + cl;
    const f32x4 bv0 = *(const f32x4*)bp;
    const f32x4 bv1 = *(const f32x4*)(bp + 4);

    for (int g = bic * 4 + wid; g < NGROUP; g += AGG_BPC * 4) {
        const int node = g * 16 + seg;
        const int beg = offsets[node];
        const int end = offsets[node + 1];

        float a[8];
#pragma unroll
        for (int i = 0; i < 8; ++i) a[i] = 0.f;

        int j = beg;
        for (; j + 3 < end; j += 4) {
            int s0 = edge_src[j];
            int s1 = edge_src[j + 1];
            int s2 = edge_src[j + 2];
            int s3 = edge_src[j + 3];
            uint4 q0 = *(const uint4*)(Ybase + (size_t)s0 * 32 + cl);
            uint4 q1 = *(const uint4*)(Ybase + (size_t)s1 * 32 + cl);
            uint4 q2 = *(const uint4*)(Ybase + (size_t)s2 * 32 + cl);
            uint4 q3 = *(const uint4*)(Ybase + (size_t)s3 * 32 + cl);
#pragma unroll
            for (int k = 0; k < 4; ++k) {
                uint4 q = k == 0 ? q0 : k == 1 ? q1 : k == 2 ? q2 : q3;
                u32 w0 = q.x, w1 = q.y, w2 = q.z, w3 = q.w;
                a[0] += __uint_as_float(w0 << 16);
                a[1] += __uint_as_float(w0 & 0xffff0000u);
                a[2] += __uint_as_float(w1 << 16);
                a[3] += __uint_as_float(w1 & 0xffff0000u);
                a[4] += __uint_as_float(w2 << 16);
                a[5] += __uint_as_float(w2 & 0xffff0000u);
                a[6] += __uint_as_float(w3 << 16);
                a[7] += __uint_as_float(w3 & 0xffff0000u);
            }
        }
        for (; j < end; ++j) {
            int s0 = edge_src[j];
            uint4 q = *(const uint4*)(Ybase + (size_t)s0 * 32 + cl);
            u32 w0 = q.x, w1 = q.y, w2 = q.z, w3 = q.w;
            a[0] += __uint_as_float(w0 << 16);
            a[1] += __uint_as_float(w0 & 0xffff0000u);
            a[2] += __uint_as_float(w1 << 16);
            a[3] += __uint_as_float(w1 & 0xffff0000u);
            a[4] += __uint_as_float(w2 << 16);
            a[5] += __uint_as_float(w2 & 0xffff0000u);
            a[6] += __uint_as_float(w3 << 16);
            a[7] += __uint_as_float(w3 & 0xffff0000u);
        }

        const int deg = end - beg;
        f32x4 r0, r1;
        if (deg > 0) {
            float inv = 1.0f / (float)deg;
#pragma unroll
            for (int i = 0; i < 4; ++i) {
                r0[i] = a[i] * inv + bv0[i];
                r1[i] = a[4 + i] * inv + bv1[i];
            }
        } else {
            uint4 q = *(const uint4*)(Ybase + (size_t)node * 32 + cl);
            u32 w[4] = {q.x, q.y, q.z, q.w};
#pragma unroll
            for (int i = 0; i < 4; ++i) {
                float lo = __uint_as_float(w[i] << 16);
                float hi = __uint_as_float(w[i] & 0xffff0000u);
                if (i < 2) { r0[2*i] = lo + bv0[2*i]; r0[2*i+1] = hi + bv0[2*i+1]; }
                else { r1[2*(i-2)] = lo + bv1[2*(i-2)]; r1[2*(i-2)+1] = hi + bv1[2*(i-2)+1]; }
            }
        }
        // seg (4 lanes) writes 128B contiguous f32
        float* op = out + (size_t)node * DIM + chunk * 32 + cl;
        *(f32x4*)op = r0;
        *(f32x4*)(op + 4) = r1;
    }
}

static inline size_t align64(size_t x) { return (x + 63) & ~(size_t)63; }

extern "C" void kernel_launch(void* const* d_in, const int* in_sizes, int n_in,
                              void* d_out, int out_size, void* d_ws, size_t ws_size,
                              hipStream_t stream) {
    const float* feature = (const float*)d_in[0];
    const int*   src     = (const int*)d_in[1];
    const int*   dst     = (const int*)d_in[2];
    const float* W       = (const float*)d_in[3];
    const float* b       = (const float*)d_in[4];
    float* out = (float*)d_out;

    // workspace layout (~38.8 MB total)
    char* ws = (char*)d_ws;
    __bf16* Yc  = (__bf16*)ws;               ws += align64((size_t)N_NODES * DIM * 2);
    __bf16* Wbf = (__bf16*)ws;               ws += align64((size_t)DIM * DIM * 2);
    int* offsets  = (int*)ws;                ws += align64((size_t)(N_NODES + 1) * 4);
    int* gbkt     = (int*)ws;                ws += align64((size_t)NBUK * 4);
    int* bbase    = (int*)ws;                ws += align64((size_t)NBUK * 4);
    int* bcur     = (int*)ws;                ws += align64((size_t)NBUK * 4);
    unsigned int* staged = (unsigned int*)ws; ws += align64((size_t)N_EDGES * 4);
    int* edge_src = (int*)ws;                ws += align64((size_t)N_EDGES * 4);

    hipMemsetAsync(gbkt, 0, (size_t)NBUK * 4, stream);

    convw_k<<<(DIM * DIM + 255) / 256, 256, 0, stream>>>(W, Wbf);
    gemm_y<<<(N_NODES + 63) / 64, 256, 0, stream>>>(feature, Wbf, Yc);
    count_k<<<NBLK, 256, 0, stream>>>(dst, gbkt);
    scanB_k<<<1, 256, 0, stream>>>(gbkt, bbase, bcur, offsets);
    place_k<<<NBLK, 256, 0, stream>>>(src, dst, bcur, staged);
    finalize_k<<<NBUK, 256, 0, stream>>>(staged, bbase, gbkt, offsets, edge_src);
    aggregate_k<<<NCHUNK * AGG_BPC, 256, 0, stream>>>(Yc, offsets, edge_src, b, out);
}

// Round 9
// 195.799 us; speedup vs baseline: 2.2136x; 1.2341x over previous
//
#include <hip/hip_runtime.h>
#include <hip/hip_bf16.h>

#define N_NODES 50000
#define DIM 256
#define N_EDGES 1600000
#define NBUK 196            // buckets of 256 nodes: 196*256 = 50176 >= 50000
#define CAP 10240           // fixed bucket region capacity (mean 8163, +23 sigma)
#define CHUNK_E 4096        // edges per binning block
#define NBLK ((N_EDGES + CHUNK_E - 1) / CHUNK_E)   // 391
#define GEMM_BLKS ((N_NODES + 63) / 64)            // 782
#define NCHUNK 8            // Y column chunks (32 cols each), one per XCD
#define AGG_BPC 391         // aggregate blocks per chunk
#define NGROUP (N_NODES / 16)  // 3125 groups of 16 nodes

typedef float f32x4 __attribute__((ext_vector_type(4)));
typedef __bf16 bf16x8 __attribute__((ext_vector_type(8)));
typedef __bf16 bf16x4 __attribute__((ext_vector_type(4)));
typedef unsigned int u32;
typedef unsigned short u16;

// ---------------- setup: W -> bf16, init bucket cursors ----------------
__global__ __launch_bounds__(256) void setup_k(const float* __restrict__ W,
                                               __bf16* __restrict__ Wbf,
                                               int* __restrict__ bcur) {
    int i = blockIdx.x * 256 + threadIdx.x;   // grid = 256 blocks: i in [0, 65536)
    Wbf[i] = (__bf16)W[i];
    if (i < NBUK) bcur[i] = i * CAP;
}

// ---------------- fused: gemm role (blocks < GEMM_BLKS) | place role ----------
// gemm: Y = feature @ W.T via swapped-operand MFMA; Yc[chunk][node][32].
// place: bin edges into fixed-cap bucket regions of `staged`.
__global__ __launch_bounds__(256) void fused_k(const float* __restrict__ feat,
                                               const __bf16* __restrict__ Wbf,
                                               __bf16* __restrict__ Yc,
                                               const int* __restrict__ src,
                                               const int* __restrict__ dst,
                                               int* __restrict__ bcur,
                                               unsigned int* __restrict__ staged) {
    __shared__ int lh[NBUK];
    __shared__ int lbase[NBUK];

    if (blockIdx.x < GEMM_BLKS) {
        // ---- GEMM role ----
        const int wid  = threadIdx.x >> 6;
        const int lane = threadIdx.x & 63;
        const int row0 = blockIdx.x * 64 + wid * 16;
        const int mrow = lane & 15;
        const int kgrp = lane >> 4;          // 0..3

        int arow = row0 + mrow;
        int arow_c = arow < N_NODES ? arow : (N_NODES - 1);
        const float* aptr = feat + (size_t)arow_c * DIM + kgrp * 8;

        f32x4 acc[16];
#pragma unroll
        for (int i = 0; i < 16; ++i) acc[i] = (f32x4)0.0f;

#pragma unroll
        for (int ks = 0; ks < 8; ++ks) {
            const float* ap = aptr + ks * 32;
            f32x4 a0 = *(const f32x4*)(ap);
            f32x4 a1 = *(const f32x4*)(ap + 4);
            bf16x8 af;                        // feat fragment: n-side after swap
            af[0] = (__bf16)a0[0]; af[1] = (__bf16)a0[1];
            af[2] = (__bf16)a0[2]; af[3] = (__bf16)a0[3];
            af[4] = (__bf16)a1[0]; af[5] = (__bf16)a1[1];
            af[6] = (__bf16)a1[2]; af[7] = (__bf16)a1[3];
#pragma unroll
            for (int nt = 0; nt < 16; ++nt) {
                int ncol = nt * 16 + mrow;   // W row (outcol): m-side
                const bf16x8 wf = *(const bf16x8*)(Wbf + (size_t)ncol * DIM + ks * 32 + kgrp * 8);
                acc[nt] = __builtin_amdgcn_mfma_f32_16x16x32_bf16(wf, af, acc[nt], 0, 0, 0);
            }
        }

        // D layout (m89): col(lane&15)=node, row((lane>>4)*4+r)=outcol-in-tile
        const int node = row0 + mrow;
        if (node < N_NODES) {
#pragma unroll
            for (int nt = 0; nt < 16; ++nt) {
                int oc0 = nt * 16 + kgrp * 4;
                bf16x4 pv;
                pv[0] = (__bf16)acc[nt][0];
                pv[1] = (__bf16)acc[nt][1];
                pv[2] = (__bf16)acc[nt][2];
                pv[3] = (__bf16)acc[nt][3];
                __bf16* yp = Yc + (size_t)(oc0 >> 5) * N_NODES * 32
                                + (size_t)node * 32 + (oc0 & 31);
                *(bf16x4*)yp = pv;
            }
        }
    } else {
        // ---- place role ----
        int pb = blockIdx.x - GEMM_BLKS;     // 0..NBLK-1
        for (int i = threadIdx.x; i < NBUK; i += 256) lh[i] = 0;
        __syncthreads();
        int base = pb * CHUNK_E;
        int end = base + CHUNK_E; if (end > N_EDGES) end = N_EDGES;
        for (int e = base + threadIdx.x; e < end; e += 256)
            atomicAdd(&lh[dst[e] >> 8], 1);
        __syncthreads();
        for (int i = threadIdx.x; i < NBUK; i += 256) {
            int c = lh[i];
            lbase[i] = c ? atomicAdd(&bcur[i], c) : 0;
            lh[i] = 0;                 // reuse as local cursor
        }
        __syncthreads();
        for (int e = base + threadIdx.x; e < end; e += 256) {
            int d = dst[e];
            int s = src[e];            // < 50000 -> fits in 16 bits
            int b = d >> 8;
            int p = atomicAdd(&lh[b], 1);
            staged[lbase[b] + p] = (unsigned int)s | ((unsigned int)(d & 255) << 16);
        }
    }
}

// ---------------- per-bucket finalize: node offsets/degrees + u16 edge lists ----
__global__ __launch_bounds__(256) void finalize_k(const unsigned int* __restrict__ staged,
                                                  const int* __restrict__ bcur,
                                                  int* __restrict__ offs,
                                                  u16* __restrict__ deg16,
                                                  u16* __restrict__ edge16) {
    __shared__ int nh[256];
    __shared__ int nbase[256];
    __shared__ int sm[256];
    int t = threadIdx.x, b = blockIdx.x;
    int beg = b * CAP;
    int cnt = bcur[b] - beg;
    nh[t] = 0;
    __syncthreads();
    for (int i = t; i < cnt; i += 256)
        atomicAdd(&nh[staged[beg + i] >> 16], 1);
    __syncthreads();
    int v = nh[t];
    sm[t] = v;
    __syncthreads();
    for (int off = 1; off < 256; off <<= 1) {
        int x = (t >= off) ? sm[t - off] : 0;
        __syncthreads();
        sm[t] += x;
        __syncthreads();
    }
    nbase[t] = sm[t] - v;
    int node = (b << 8) + t;
    if (node < N_NODES) {
        offs[node]  = beg + nbase[t];
        deg16[node] = (u16)v;
    }
    nh[t] = 0;                     // reuse as per-node cursor
    __syncthreads();
    for (int i = t; i < cnt; i += 256) {
        unsigned int u = staged[beg + i];
        int dl = (int)(u >> 16);
        int p = atomicAdd(&nh[dl], 1);
        edge16[beg + nbase[dl] + p] = (u16)(u & 0xFFFFu);
    }
}

// ---------------- per-node gather-mean + bias, column-chunked, wide gather -----
// chunk = blockIdx & 7 (XCD round-robin); per-XCD working set = 3.2MB (L2-resident)
// wave = 16 nodes; segment (4 lanes) owns one node; lane covers 8 cols (16B/edge).
__global__ __launch_bounds__(256) void aggregate_k(const __bf16* __restrict__ Yc,
                                                   const int* __restrict__ offs,
                                                   const u16* __restrict__ deg16,
                                                   const u16* __restrict__ edge16,
                                                   const float* __restrict__ bias,
                                                   float* __restrict__ out) {
    const int chunk = blockIdx.x & 7;
    const int bic   = blockIdx.x >> 3;      // block index within chunk
    const int wid   = threadIdx.x >> 6;
    const int lane  = threadIdx.x & 63;
    const int seg   = lane >> 2;            // node slot 0..15
    const int cl    = (lane & 3) * 8;       // bf16 col within chunk: 0,8,16,24

    const __bf16* Ybase = Yc + (size_t)chunk * N_NODES * 32;
    const float* bp = bias + chunk * 32 + cl;
    const f32x4 bv0 = *(const f32x4*)bp;
    const f32x4 bv1 = *(const f32x4*)(bp + 4);

    for (int g = bic * 4 + wid; g < NGROUP; g += AGG_BPC * 4) {
        const int node = g * 16 + seg;
        const int beg = offs[node];
        const int dg  = (int)deg16[node];
        const int end = beg + dg;

        float a[8];
#pragma unroll
        for (int i = 0; i < 8; ++i) a[i] = 0.f;

        int j = beg;
        for (; j + 3 < end; j += 4) {
            int s0 = edge16[j];
            int s1 = edge16[j + 1];
            int s2 = edge16[j + 2];
            int s3 = edge16[j + 3];
            uint4 q0 = *(const uint4*)(Ybase + (size_t)s0 * 32 + cl);
            uint4 q1 = *(const uint4*)(Ybase + (size_t)s1 * 32 + cl);
            uint4 q2 = *(const uint4*)(Ybase + (size_t)s2 * 32 + cl);
            uint4 q3 = *(const uint4*)(Ybase + (size_t)s3 * 32 + cl);
#pragma unroll
            for (int k = 0; k < 4; ++k) {
                uint4 q = k == 0 ? q0 : k == 1 ? q1 : k == 2 ? q2 : q3;
                u32 w0 = q.x, w1 = q.y, w2 = q.z, w3 = q.w;
                a[0] += __uint_as_float(w0 << 16);
                a[1] += __uint_as_float(w0 & 0xffff0000u);
                a[2] += __uint_as_float(w1 << 16);
                a[3] += __uint_as_float(w1 & 0xffff0000u);
                a[4] += __uint_as_float(w2 << 16);
                a[5] += __uint_as_float(w2 & 0xffff0000u);
                a[6] += __uint_as_float(w3 << 16);
                a[7] += __uint_as_float(w3 & 0xffff0000u);
            }
        }
        for (; j < end; ++j) {
            int s0 = edge16[j];
            uint4 q = *(const uint4*)(Ybase + (size_t)s0 * 32 + cl);
            u32 w0 = q.x, w1 = q.y, w2 = q.z, w3 = q.w;
            a[0] += __uint_as_float(w0 << 16);
            a[1] += __uint_as_float(w0 & 0xffff0000u);
            a[2] += __uint_as_float(w1 << 16);
            a[3] += __uint_as_float(w1 & 0xffff0000u);
            a[4] += __uint_as_float(w2 << 16);
            a[5] += __uint_as_float(w2 & 0xffff0000u);
            a[6] += __uint_as_float(w3 << 16);
            a[7] += __uint_as_float(w3 & 0xffff0000u);
        }

        f32x4 r0, r1;
        if (dg > 0) {
            float inv = 1.0f / (float)dg;
#pragma unroll
            for (int i = 0; i < 4; ++i) {
                r0[i] = a[i] * inv + bv0[i];
                r1[i] = a[4 + i] * inv + bv1[i];
            }
        } else {
            uint4 q = *(const uint4*)(Ybase + (size_t)node * 32 + cl);
            u32 w[4] = {q.x, q.y, q.z, q.w};
#pragma unroll
            for (int i = 0; i < 4; ++i) {
                float lo = __uint_as_float(w[i] << 16);
                float hi = __uint_as_float(w[i] & 0xffff0000u);
                if (i < 2) { r0[2*i] = lo + bv0[2*i]; r0[2*i+1] = hi + bv0[2*i+1]; }
                else { r1[2*(i-2)] = lo + bv1[2*(i-2)]; r1[2*(i-2)+1] = hi + bv1[2*(i-2)+1]; }
            }
        }
        // segment (4 lanes) writes 128B contiguous f32
        float* op = out + (size_t)node * DIM + chunk * 32 + cl;
        *(f32x4*)op = r0;
        *(f32x4*)(op + 4) = r1;
    }
}

static inline size_t align64(size_t x) { return (x + 63) & ~(size_t)63; }

extern "C" void kernel_launch(void* const* d_in, const int* in_sizes, int n_in,
                              void* d_out, int out_size, void* d_ws, size_t ws_size,
                              hipStream_t stream) {
    const float* feature = (const float*)d_in[0];
    const int*   src     = (const int*)d_in[1];
    const int*   dst     = (const int*)d_in[2];
    const float* W       = (const float*)d_in[3];
    const float* b       = (const float*)d_in[4];
    float* out = (float*)d_out;

    // workspace layout (~38.1 MB total)
    char* ws = (char*)d_ws;
    __bf16* Yc  = (__bf16*)ws;               ws += align64((size_t)N_NODES * DIM * 2);
    __bf16* Wbf = (__bf16*)ws;               ws += align64((size_t)DIM * DIM * 2);
    int* offs     = (int*)ws;                ws += align64((size_t)N_NODES * 4);
    u16* deg16    = (u16*)ws;                ws += align64((size_t)N_NODES * 2);
    int* bcur     = (int*)ws;                ws += align64((size_t)NBUK * 4);
    unsigned int* staged = (unsigned int*)ws; ws += align64((size_t)NBUK * CAP * 4);
    u16* edge16   = (u16*)ws;                ws += align64((size_t)NBUK * CAP * 2);

    setup_k<<<(DIM * DIM) / 256, 256, 0, stream>>>(W, Wbf, bcur);
    fused_k<<<GEMM_BLKS + NBLK, 256, 0, stream>>>(feature, Wbf, Yc, src, dst, bcur, staged);
    finalize_k<<<NBUK, 256, 0, stream>>>(staged, bcur, offs, deg16, edge16);
    aggregate_k<<<NCHUNK * AGG_BPC, 256, 0, stream>>>(Yc, offs, deg16, edge16, b, out);
}

// Round 10
// 188.950 us; speedup vs baseline: 2.2939x; 1.0362x over previous
//
#include <hip/hip_runtime.h>
#include <hip/hip_bf16.h>

#define N_NODES 50000
#define NPAD 50016          // Yc row stride: N_NODES padded; rows >= N_NODES are zero
#define DUMMY 50000         // dummy src index -> zero row (padding contributes 0)
#define DIM 256
#define N_EDGES 1600000
#define NBUK 196            // buckets of 256 nodes: 196*256 = 50176 >= 50000
#define CAP 10240           // fixed bucket region capacity (mean 8163 + pad <= ~9700)
#define CHUNK_E 4096        // edges per binning block
#define NBLK ((N_EDGES + CHUNK_E - 1) / CHUNK_E)   // 391
#define GEMM_BLKS ((N_NODES + 63) / 64)            // 782
#define NCHUNK 8            // Y column chunks (32 cols each), one per XCD
#define AGG_BPC 391         // aggregate blocks per chunk
#define NGROUP (N_NODES / 16)  // 3125 groups of 16 nodes

typedef float f32x4 __attribute__((ext_vector_type(4)));
typedef __bf16 bf16x8 __attribute__((ext_vector_type(8)));
typedef __bf16 bf16x4 __attribute__((ext_vector_type(4)));
typedef unsigned long long u64;
typedef unsigned int u32;
typedef unsigned short u16;

// ---------------- setup: W -> bf16, init bucket cursors, zero dummy Y rows -----
__global__ __launch_bounds__(256) void setup_k(const float* __restrict__ W,
                                               __bf16* __restrict__ Wbf,
                                               int* __restrict__ bcur,
                                               __bf16* __restrict__ Yc) {
    int i = blockIdx.x * 256 + threadIdx.x;   // grid = 256 blocks: i in [0, 65536)
    Wbf[i] = (__bf16)W[i];
    if (i < NBUK) bcur[i] = i * CAP;
    if (i < NCHUNK * (NPAD - N_NODES) * 32) {  // zero the 16 pad rows per chunk
        int c = i >> 9;            // 16*32 = 512 elems per chunk
        int rem = i & 511;
        Yc[(size_t)c * NPAD * 32 + (size_t)(N_NODES + (rem >> 5)) * 32 + (rem & 31)] = (__bf16)0.0f;
    }
}

// ---------------- fused: gemm role (blocks < GEMM_BLKS) | place role ----------
// gemm: Y = feature @ W.T via swapped-operand MFMA; Yc[chunk][node][32].
//   Per ks: ALL 16 B-fragments issued as independent loads (one wait), then
//   16 MFMAs -- batches the L2 latency instead of serializing it per-MFMA.
// place: bin edges into fixed-cap bucket regions of `staged`.
__global__ __launch_bounds__(256) void fused_k(const float* __restrict__ feat,
                                               const __bf16* __restrict__ Wbf,
                                               __bf16* __restrict__ Yc,
                                               const int* __restrict__ src,
                                               const int* __restrict__ dst,
                                               int* __restrict__ bcur,
                                               unsigned int* __restrict__ staged) {
    __shared__ int lh[NBUK];
    __shared__ int lbase[NBUK];

    if (blockIdx.x < GEMM_BLKS) {
        // ---- GEMM role ----
        const int wid  = threadIdx.x >> 6;
        const int lane = threadIdx.x & 63;
        const int row0 = blockIdx.x * 64 + wid * 16;
        const int mrow = lane & 15;
        const int kgrp = lane >> 4;          // 0..3

        int arow = row0 + mrow;
        int arow_c = arow < N_NODES ? arow : (N_NODES - 1);
        const float* aptr = feat + (size_t)arow_c * DIM + kgrp * 8;

        // preload + convert ALL A fragments (8 ks x bf16x8 = 32 VGPR)
        f32x4 araw[16];
#pragma unroll
        for (int ks = 0; ks < 8; ++ks) {
            araw[2 * ks]     = *(const f32x4*)(aptr + ks * 32);
            araw[2 * ks + 1] = *(const f32x4*)(aptr + ks * 32 + 4);
        }
        bf16x8 af[8];
#pragma unroll
        for (int ks = 0; ks < 8; ++ks) {
            af[ks][0] = (__bf16)araw[2*ks][0];   af[ks][1] = (__bf16)araw[2*ks][1];
            af[ks][2] = (__bf16)araw[2*ks][2];   af[ks][3] = (__bf16)araw[2*ks][3];
            af[ks][4] = (__bf16)araw[2*ks+1][0]; af[ks][5] = (__bf16)araw[2*ks+1][1];
            af[ks][6] = (__bf16)araw[2*ks+1][2]; af[ks][7] = (__bf16)araw[2*ks+1][3];
        }

        f32x4 acc[16];
#pragma unroll
        for (int i = 0; i < 16; ++i) acc[i] = (f32x4)0.0f;

#pragma unroll
        for (int ks = 0; ks < 8; ++ks) {
            bf16x8 wf[16];
#pragma unroll
            for (int nt = 0; nt < 16; ++nt)
                wf[nt] = *(const bf16x8*)(Wbf + (size_t)(nt * 16 + mrow) * DIM + ks * 32 + kgrp * 8);
#pragma unroll
            for (int nt = 0; nt < 16; ++nt)
                acc[nt] = __builtin_amdgcn_mfma_f32_16x16x32_bf16(wf[nt], af[ks], acc[nt], 0, 0, 0);
        }

        // D layout (m89): col(lane&15)=node, row((lane>>4)*4+r)=outcol-in-tile
        const int node = row0 + mrow;
        if (node < N_NODES) {
#pragma unroll
            for (int nt = 0; nt < 16; ++nt) {
                int oc0 = nt * 16 + kgrp * 4;
                bf16x4 pv;
                pv[0] = (__bf16)acc[nt][0];
                pv[1] = (__bf16)acc[nt][1];
                pv[2] = (__bf16)acc[nt][2];
                pv[3] = (__bf16)acc[nt][3];
                __bf16* yp = Yc + (size_t)(oc0 >> 5) * NPAD * 32
                                + (size_t)node * 32 + (oc0 & 31);
                *(bf16x4*)yp = pv;
            }
        }
    } else {
        // ---- place role ----
        int pb = blockIdx.x - GEMM_BLKS;     // 0..NBLK-1
        for (int i = threadIdx.x; i < NBUK; i += 256) lh[i] = 0;
        __syncthreads();
        int base = pb * CHUNK_E;
        int end = base + CHUNK_E; if (end > N_EDGES) end = N_EDGES;
        for (int e = base + threadIdx.x; e < end; e += 256)
            atomicAdd(&lh[dst[e] >> 8], 1);
        __syncthreads();
        for (int i = threadIdx.x; i < NBUK; i += 256) {
            int c = lh[i];
            lbase[i] = c ? atomicAdd(&bcur[i], c) : 0;
            lh[i] = 0;                 // reuse as local cursor
        }
        __syncthreads();
        for (int e = base + threadIdx.x; e < end; e += 256) {
            int d = dst[e];
            int s = src[e];            // < 50000 -> fits in 16 bits
            int b = d >> 8;
            int p = atomicAdd(&lh[b], 1);
            staged[lbase[b] + p] = (unsigned int)s | ((unsigned int)(d & 255) << 16);
        }
    }
}

// ---------------- per-bucket finalize: node offsets/degrees + u16 edge lists ----
// Per-node lists padded to a multiple of 4 with DUMMY (zero-row) indices so the
// aggregate can read aligned u64 (4 edges) with no remainder handling.
__global__ __launch_bounds__(256) void finalize_k(const unsigned int* __restrict__ staged,
                                                  const int* __restrict__ bcur,
                                                  int* __restrict__ offs,
                                                  u16* __restrict__ deg16,
                                                  u16* __restrict__ edge16) {
    __shared__ int nh[256];
    __shared__ int nbase[256];
    __shared__ int sm[256];
    int t = threadIdx.x, b = blockIdx.x;
    int beg = b * CAP;
    int cnt = bcur[b] - beg;
    nh[t] = 0;
    __syncthreads();
    for (int i = t; i < cnt; i += 256)
        atomicAdd(&nh[staged[beg + i] >> 16], 1);
    __syncthreads();
    int v = nh[t];
    int v4 = (v + 3) & ~3;         // padded count
    sm[t] = v4;
    __syncthreads();
    for (int off = 1; off < 256; off <<= 1) {
        int x = (t >= off) ? sm[t - off] : 0;
        __syncthreads();
        sm[t] += x;
        __syncthreads();
    }
    nbase[t] = sm[t] - v4;         // exclusive prefix of padded counts (4-aligned)
    int node = (b << 8) + t;
    if (node < N_NODES) {
        offs[node]  = beg + nbase[t];
        deg16[node] = (u16)v;
    }
    // fill the pad slots with DUMMY
    for (int i = v; i < v4; ++i)
        edge16[beg + nbase[t] + i] = (u16)DUMMY;
    nh[t] = 0;                     // reuse as per-node cursor
    __syncthreads();
    for (int i = t; i < cnt; i += 256) {
        unsigned int u = staged[beg + i];
        int dl = (int)(u >> 16);
        int p = atomicAdd(&nh[dl], 1);
        edge16[beg + nbase[dl] + p] = (u16)(u & 0xFFFFu);
    }
}

// ---------------- per-node gather-mean + bias, column-chunked, u64 edge loads --
// chunk = blockIdx & 7 (XCD round-robin); per-XCD working set = 3.2MB (L2-resident)
// wave = 16 nodes; segment (4 lanes) owns one node; lane covers 8 cols (16B/edge).
// Edge lists 4-padded: u64 load = 4 edges; 8 edges (2 u64) per unrolled step.
__global__ __launch_bounds__(256) void aggregate_k(const __bf16* __restrict__ Yc,
                                                   const int* __restrict__ offs,
                                                   const u16* __restrict__ deg16,
                                                   const u16* __restrict__ edge16,
                                                   const float* __restrict__ bias,
                                                   float* __restrict__ out) {
    const int chunk = blockIdx.x & 7;
    const int bic   = blockIdx.x >> 3;      // block index within chunk
    const int wid   = threadIdx.x >> 6;
    const int lane  = threadIdx.x & 63;
    const int seg   = lane >> 2;            // node slot 0..15
    const int cl    = (lane & 3) * 8;       // bf16 col within chunk: 0,8,16,24

    const __bf16* Ybase = Yc + (size_t)chunk * NPAD * 32;
    const float* bp = bias + chunk * 32 + cl;
    const f32x4 bv0 = *(const f32x4*)bp;
    const f32x4 bv1 = *(const f32x4*)(bp + 4);

    for (int g = bic * 4 + wid; g < NGROUP; g += AGG_BPC * 4) {
        const int node = g * 16 + seg;
        const int beg = offs[node];
        const int dg  = (int)deg16[node];
        const int end4 = beg + ((dg + 3) & ~3);

        float a[8];
#pragma unroll
        for (int i = 0; i < 8; ++i) a[i] = 0.f;

        int j = beg;
        for (; j + 7 < end4; j += 8) {
            u64 e0 = *(const u64*)(edge16 + j);
            u64 e1 = *(const u64*)(edge16 + j + 4);
            uint4 q0 = *(const uint4*)(Ybase + (size_t)(e0 & 0xffff) * 32 + cl);
            uint4 q1 = *(const uint4*)(Ybase + (size_t)((e0 >> 16) & 0xffff) * 32 + cl);
            uint4 q2 = *(const uint4*)(Ybase + (size_t)((e0 >> 32) & 0xffff) * 32 + cl);
            uint4 q3 = *(const uint4*)(Ybase + (size_t)(e0 >> 48) * 32 + cl);
            uint4 q4 = *(const uint4*)(Ybase + (size_t)(e1 & 0xffff) * 32 + cl);
            uint4 q5 = *(const uint4*)(Ybase + (size_t)((e1 >> 16) & 0xffff) * 32 + cl);
            uint4 q6 = *(const uint4*)(Ybase + (size_t)((e1 >> 32) & 0xffff) * 32 + cl);
            uint4 q7 = *(const uint4*)(Ybase + (size_t)(e1 >> 48) * 32 + cl);
#pragma unroll
            for (int k = 0; k < 8; ++k) {
                uint4 q = k==0?q0:k==1?q1:k==2?q2:k==3?q3:k==4?q4:k==5?q5:k==6?q6:q7;
                a[0] += __uint_as_float(q.x << 16);
                a[1] += __uint_as_float(q.x & 0xffff0000u);
                a[2] += __uint_as_float(q.y << 16);
                a[3] += __uint_as_float(q.y & 0xffff0000u);
                a[4] += __uint_as_float(q.z << 16);
                a[5] += __uint_as_float(q.z & 0xffff0000u);
                a[6] += __uint_as_float(q.w << 16);
                a[7] += __uint_as_float(q.w & 0xffff0000u);
            }
        }
        for (; j < end4; j += 4) {
            u64 e0 = *(const u64*)(edge16 + j);
            uint4 q0 = *(const uint4*)(Ybase + (size_t)(e0 & 0xffff) * 32 + cl);
            uint4 q1 = *(const uint4*)(Ybase + (size_t)((e0 >> 16) & 0xffff) * 32 + cl);
            uint4 q2 = *(const uint4*)(Ybase + (size_t)((e0 >> 32) & 0xffff) * 32 + cl);
            uint4 q3 = *(const uint4*)(Ybase + (size_t)(e0 >> 48) * 32 + cl);
#pragma unroll
            for (int k = 0; k < 4; ++k) {
                uint4 q = k==0?q0:k==1?q1:k==2?q2:q3;
                a[0] += __uint_as_float(q.x << 16);
                a[1] += __uint_as_float(q.x & 0xffff0000u);
                a[2] += __uint_as_float(q.y << 16);
                a[3] += __uint_as_float(q.y & 0xffff0000u);
                a[4] += __uint_as_float(q.z << 16);
                a[5] += __uint_as_float(q.z & 0xffff0000u);
                a[6] += __uint_as_float(q.w << 16);
                a[7] += __uint_as_float(q.w & 0xffff0000u);
            }
        }

        f32x4 r0, r1;
        if (dg > 0) {
            float inv = 1.0f / (float)dg;
#pragma unroll
            for (int i = 0; i < 4; ++i) {
                r0[i] = a[i] * inv + bv0[i];
                r1[i] = a[4 + i] * inv + bv1[i];
            }
        } else {
            uint4 q = *(const uint4*)(Ybase + (size_t)node * 32 + cl);
            u32 w[4] = {q.x, q.y, q.z, q.w};
#pragma unroll
            for (int i = 0; i < 4; ++i) {
                float lo = __uint_as_float(w[i] << 16);
                float hi = __uint_as_float(w[i] & 0xffff0000u);
                if (i < 2) { r0[2*i] = lo + bv0[2*i]; r0[2*i+1] = hi + bv0[2*i+1]; }
                else { r1[2*(i-2)] = lo + bv1[2*(i-2)]; r1[2*(i-2)+1] = hi + bv1[2*(i-2)+1]; }
            }
        }
        // segment (4 lanes) writes 128B contiguous f32
        float* op = out + (size_t)node * DIM + chunk * 32 + cl;
        *(f32x4*)op = r0;
        *(f32x4*)(op + 4) = r1;
    }
}

static inline size_t align64(size_t x) { return (x + 63) & ~(size_t)63; }

extern "C" void kernel_launch(void* const* d_in, const int* in_sizes, int n_in,
                              void* d_out, int out_size, void* d_ws, size_t ws_size,
                              hipStream_t stream) {
    const float* feature = (const float*)d_in[0];
    const int*   src     = (const int*)d_in[1];
    const int*   dst     = (const int*)d_in[2];
    const float* W       = (const float*)d_in[3];
    const float* b       = (const float*)d_in[4];
    float* out = (float*)d_out;

    // workspace layout (~38.2 MB total)
    char* ws = (char*)d_ws;
    __bf16* Yc  = (__bf16*)ws;               ws += align64((size_t)NCHUNK * NPAD * 32 * 2);
    __bf16* Wbf = (__bf16*)ws;               ws += align64((size_t)DIM * DIM * 2);
    int* offs     = (int*)ws;                ws += align64((size_t)N_NODES * 4);
    u16* deg16    = (u16*)ws;                ws += align64((size_t)N_NODES * 2);
    int* bcur     = (int*)ws;                ws += align64((size_t)NBUK * 4);
    unsigned int* staged = (unsigned int*)ws; ws += align64((size_t)NBUK * CAP * 4);
    u16* edge16   = (u16*)ws;                ws += align64((size_t)NBUK * CAP * 2);

    setup_k<<<(DIM * DIM) / 256, 256, 0, stream>>>(W, Wbf, bcur, Yc);
    fused_k<<<GEMM_BLKS + NBLK, 256, 0, stream>>>(feature, Wbf, Yc, src, dst, bcur, staged);
    finalize_k<<<NBUK, 256, 0, stream>>>(staged, bcur, offs, deg16, edge16);
    aggregate_k<<<NCHUNK * AGG_BPC, 256, 0, stream>>>(Yc, offs, deg16, edge16, b, out);
}

// Round 11
// 154.751 us; speedup vs baseline: 2.8008x; 1.2210x over previous
//
#include <hip/hip_runtime.h>
#include <hip/hip_bf16.h>

#define N_NODES 50000
#define NPAD 50016          // Yc row stride: N_NODES padded; rows >= N_NODES are zero
#define DUMMY 50000         // dummy src index -> zero row (padding contributes 0)
#define DIM 256
#define N_EDGES 1600000
#define NBUK 196            // buckets of 256 nodes: 196*256 = 50176 >= 50000
#define CAP 10240           // fixed bucket region capacity (mean 8163 + pad <= ~9700)
#define CHUNK_E 4096        // edges per binning block
#define NBLK ((N_EDGES + CHUNK_E - 1) / CHUNK_E)   // 391
#define GEMM_BLKS ((N_NODES + 63) / 64)            // 782
#define NCHUNK 8            // Y column chunks (32 cols each), one per XCD
#define AGG_BPC 391         // aggregate blocks per chunk
#define NGROUP (N_NODES / 16)  // 3125 groups of 16 nodes
#define LROW 72             // LDS W-tile row stride in bf16 (144 B, not 0 mod 128B)

typedef float f32x4 __attribute__((ext_vector_type(4)));
typedef __bf16 bf16x8 __attribute__((ext_vector_type(8)));
typedef __bf16 bf16x4 __attribute__((ext_vector_type(4)));
typedef unsigned long long u64;
typedef unsigned int u32;
typedef unsigned short u16;

// ---------------- setup: W -> bf16, init bucket cursors, zero dummy Y rows -----
__global__ __launch_bounds__(256) void setup_k(const float* __restrict__ W,
                                               __bf16* __restrict__ Wbf,
                                               int* __restrict__ bcur,
                                               __bf16* __restrict__ Yc) {
    int i = blockIdx.x * 256 + threadIdx.x;   // grid = 256 blocks: i in [0, 65536)
    Wbf[i] = (__bf16)W[i];
    if (i < NBUK) bcur[i] = i * CAP;
    if (i < NCHUNK * (NPAD - N_NODES) * 32) {  // zero the 16 pad rows per chunk
        int c = i >> 9;            // 16*32 = 512 elems per chunk
        int rem = i & 511;
        Yc[(size_t)c * NPAD * 32 + (size_t)(N_NODES + (rem >> 5)) * 32 + (rem & 31)] = (__bf16)0.0f;
    }
}

// ---------------- fused: gemm role (blocks < GEMM_BLKS) | place role ----------
// gemm: Y = feature @ W.T via swapped-operand MFMA; Yc[chunk][node][32].
//   W staged in LDS in 4 K-quarter phases (32KB tile, 144B padded rows) so the
//   inner loop reads fragments via ds_read_b128 (~12cyc) instead of L2 (~230cyc).
// place: bin edges into fixed-cap bucket regions of `staged`.
__global__ __launch_bounds__(256) void fused_k(const float* __restrict__ feat,
                                               const __bf16* __restrict__ Wbf,
                                               __bf16* __restrict__ Yc,
                                               const int* __restrict__ src,
                                               const int* __restrict__ dst,
                                               int* __restrict__ bcur,
                                               unsigned int* __restrict__ staged) {
    __shared__ __bf16 lw[256 * LROW];    // 36 KB W K-quarter tile
    __shared__ int lh[NBUK];
    __shared__ int lbase[NBUK];

    if (blockIdx.x < GEMM_BLKS) {
        // ---- GEMM role ----
        const int wid  = threadIdx.x >> 6;
        const int lane = threadIdx.x & 63;
        const int row0 = blockIdx.x * 64 + wid * 16;
        const int mrow = lane & 15;
        const int kgrp = lane >> 4;          // 0..3

        int arow = row0 + mrow;
        int arow_c = arow < N_NODES ? arow : (N_NODES - 1);
        const float* aptr = feat + (size_t)arow_c * DIM + kgrp * 8;

        // staging coords: thread t covers idx = i*256+t; row = idx>>3, cb = (idx&7)*8
        const int t = threadIdx.x;
        const int srow = t >> 3;             // base row (stride 32 per iter)
        const int scb  = (t & 7) * 8;        // bf16 col offset within quarter

        f32x4 acc[16];
#pragma unroll
        for (int i = 0; i < 16; ++i) acc[i] = (f32x4)0.0f;

        for (int p = 0; p < 4; ++p) {
            // issue A loads for this K-quarter early (latency hides under staging)
            f32x4 ar0 = *(const f32x4*)(aptr + (p * 2) * 32);
            f32x4 ar1 = *(const f32x4*)(aptr + (p * 2) * 32 + 4);
            f32x4 ar2 = *(const f32x4*)(aptr + (p * 2 + 1) * 32);
            f32x4 ar3 = *(const f32x4*)(aptr + (p * 2 + 1) * 32 + 4);

            if (p) __syncthreads();          // prev-phase reads done
            // stage W[:, p*64 .. p*64+64) -> lw[256][LROW]
#pragma unroll
            for (int i = 0; i < 8; ++i) {
                int row = srow + i * 32;
                uint4 v = *(const uint4*)(Wbf + (size_t)row * DIM + p * 64 + scb);
                *(uint4*)(lw + row * LROW + scb) = v;
            }
            __syncthreads();

            bf16x8 af0, af1;
            af0[0] = (__bf16)ar0[0]; af0[1] = (__bf16)ar0[1];
            af0[2] = (__bf16)ar0[2]; af0[3] = (__bf16)ar0[3];
            af0[4] = (__bf16)ar1[0]; af0[5] = (__bf16)ar1[1];
            af0[6] = (__bf16)ar1[2]; af0[7] = (__bf16)ar1[3];
            af1[0] = (__bf16)ar2[0]; af1[1] = (__bf16)ar2[1];
            af1[2] = (__bf16)ar2[2]; af1[3] = (__bf16)ar2[3];
            af1[4] = (__bf16)ar3[0]; af1[5] = (__bf16)ar3[1];
            af1[6] = (__bf16)ar3[2]; af1[7] = (__bf16)ar3[3];

#pragma unroll
            for (int nt = 0; nt < 16; ++nt) {
                const __bf16* lp = lw + (nt * 16 + mrow) * LROW + kgrp * 8;
                bf16x8 wf0 = *(const bf16x8*)(lp);
                bf16x8 wf1 = *(const bf16x8*)(lp + 32);
                acc[nt] = __builtin_amdgcn_mfma_f32_16x16x32_bf16(wf0, af0, acc[nt], 0, 0, 0);
                acc[nt] = __builtin_amdgcn_mfma_f32_16x16x32_bf16(wf1, af1, acc[nt], 0, 0, 0);
            }
        }

        // D layout (m89): col(lane&15)=node, row((lane>>4)*4+r)=outcol-in-tile
        const int node = row0 + mrow;
        if (node < N_NODES) {
#pragma unroll
            for (int nt = 0; nt < 16; ++nt) {
                int oc0 = nt * 16 + kgrp * 4;
                bf16x4 pv;
                pv[0] = (__bf16)acc[nt][0];
                pv[1] = (__bf16)acc[nt][1];
                pv[2] = (__bf16)acc[nt][2];
                pv[3] = (__bf16)acc[nt][3];
                __bf16* yp = Yc + (size_t)(oc0 >> 5) * NPAD * 32
                                + (size_t)node * 32 + (oc0 & 31);
                *(bf16x4*)yp = pv;
            }
        }
    } else {
        // ---- place role ----
        int pb = blockIdx.x - GEMM_BLKS;     // 0..NBLK-1
        for (int i = threadIdx.x; i < NBUK; i += 256) lh[i] = 0;
        __syncthreads();
        int base = pb * CHUNK_E;
        int end = base + CHUNK_E; if (end > N_EDGES) end = N_EDGES;
        for (int e = base + threadIdx.x; e < end; e += 256)
            atomicAdd(&lh[dst[e] >> 8], 1);
        __syncthreads();
        for (int i = threadIdx.x; i < NBUK; i += 256) {
            int c = lh[i];
            lbase[i] = c ? atomicAdd(&bcur[i], c) : 0;
            lh[i] = 0;                 // reuse as local cursor
        }
        __syncthreads();
        for (int e = base + threadIdx.x; e < end; e += 256) {
            int d = dst[e];
            int s = src[e];            // < 50000 -> fits in 16 bits
            int b = d >> 8;
            int p = atomicAdd(&lh[b], 1);
            staged[lbase[b] + p] = (unsigned int)s | ((unsigned int)(d & 255) << 16);
        }
    }
}

// ---------------- per-bucket finalize: node offsets/degrees + u16 edge lists ----
// Per-node lists padded to a multiple of 4 with DUMMY (zero-row) indices so the
// aggregate can read aligned u64 (4 edges) with no remainder handling.
__global__ __launch_bounds__(256) void finalize_k(const unsigned int* __restrict__ staged,
                                                  const int* __restrict__ bcur,
                                                  int* __restrict__ offs,
                                                  u16* __restrict__ deg16,
                                                  u16* __restrict__ edge16) {
    __shared__ int nh[256];
    __shared__ int nbase[256];
    __shared__ int sm[256];
    int t = threadIdx.x, b = blockIdx.x;
    int beg = b * CAP;
    int cnt = bcur[b] - beg;
    nh[t] = 0;
    __syncthreads();
    for (int i = t; i < cnt; i += 256)
        atomicAdd(&nh[staged[beg + i] >> 16], 1);
    __syncthreads();
    int v = nh[t];
    int v4 = (v + 3) & ~3;         // padded count
    sm[t] = v4;
    __syncthreads();
    for (int off = 1; off < 256; off <<= 1) {
        int x = (t >= off) ? sm[t - off] : 0;
        __syncthreads();
        sm[t] += x;
        __syncthreads();
    }
    nbase[t] = sm[t] - v4;         // exclusive prefix of padded counts (4-aligned)
    int node = (b << 8) + t;
    if (node < N_NODES) {
        offs[node]  = beg + nbase[t];
        deg16[node] = (u16)v;
    }
    // fill the pad slots with DUMMY
    for (int i = v; i < v4; ++i)
        edge16[beg + nbase[t] + i] = (u16)DUMMY;
    nh[t] = 0;                     // reuse as per-node cursor
    __syncthreads();
    for (int i = t; i < cnt; i += 256) {
        unsigned int u = staged[beg + i];
        int dl = (int)(u >> 16);
        int p = atomicAdd(&nh[dl], 1);
        edge16[beg + nbase[dl] + p] = (u16)(u & 0xFFFFu);
    }
}

// ---------------- per-node gather-mean + bias, column-chunked, u64 edge loads --
// chunk = blockIdx & 7 (XCD round-robin); per-XCD working set = 3.2MB (L2-resident)
// wave = 16 nodes; segment (4 lanes) owns one node; lane covers 8 cols (16B/edge).
// Edge lists 4-padded: u64 load = 4 edges; 8 edges (2 u64) per unrolled step.
__global__ __launch_bounds__(256) void aggregate_k(const __bf16* __restrict__ Yc,
                                                   const int* __restrict__ offs,
                                                   const u16* __restrict__ deg16,
                                                   const u16* __restrict__ edge16,
                                                   const float* __restrict__ bias,
                                                   float* __restrict__ out) {
    const int chunk = blockIdx.x & 7;
    const int bic   = blockIdx.x >> 3;      // block index within chunk
    const int wid   = threadIdx.x >> 6;
    const int lane  = threadIdx.x & 63;
    const int seg   = lane >> 2;            // node slot 0..15
    const int cl    = (lane & 3) * 8;       // bf16 col within chunk: 0,8,16,24

    const __bf16* Ybase = Yc + (size_t)chunk * NPAD * 32;
    const float* bp = bias + chunk * 32 + cl;
    const f32x4 bv0 = *(const f32x4*)bp;
    const f32x4 bv1 = *(const f32x4*)(bp + 4);

    for (int g = bic * 4 + wid; g < NGROUP; g += AGG_BPC * 4) {
        const int node = g * 16 + seg;
        const int beg = offs[node];
        const int dg  = (int)deg16[node];
        const int end4 = beg + ((dg + 3) & ~3);

        float a[8];
#pragma unroll
        for (int i = 0; i < 8; ++i) a[i] = 0.f;

        int j = beg;
        for (; j + 7 < end4; j += 8) {
            u64 e0 = *(const u64*)(edge16 + j);
            u64 e1 = *(const u64*)(edge16 + j + 4);
            uint4 q0 = *(const uint4*)(Ybase + (size_t)(e0 & 0xffff) * 32 + cl);
            uint4 q1 = *(const uint4*)(Ybase + (size_t)((e0 >> 16) & 0xffff) * 32 + cl);
            uint4 q2 = *(const uint4*)(Ybase + (size_t)((e0 >> 32) & 0xffff) * 32 + cl);
            uint4 q3 = *(const uint4*)(Ybase + (size_t)(e0 >> 48) * 32 + cl);
            uint4 q4 = *(const uint4*)(Ybase + (size_t)(e1 & 0xffff) * 32 + cl);
            uint4 q5 = *(const uint4*)(Ybase + (size_t)((e1 >> 16) & 0xffff) * 32 + cl);
            uint4 q6 = *(const uint4*)(Ybase + (size_t)((e1 >> 32) & 0xffff) * 32 + cl);
            uint4 q7 = *(const uint4*)(Ybase + (size_t)(e1 >> 48) * 32 + cl);
#pragma unroll
            for (int k = 0; k < 8; ++k) {
                uint4 q = k==0?q0:k==1?q1:k==2?q2:k==3?q3:k==4?q4:k==5?q5:k==6?q6:q7;
                a[0] += __uint_as_float(q.x << 16);
                a[1] += __uint_as_float(q.x & 0xffff0000u);
                a[2] += __uint_as_float(q.y << 16);
                a[3] += __uint_as_float(q.y & 0xffff0000u);
                a[4] += __uint_as_float(q.z << 16);
                a[5] += __uint_as_float(q.z & 0xffff0000u);
                a[6] += __uint_as_float(q.w << 16);
                a[7] += __uint_as_float(q.w & 0xffff0000u);
            }
        }
        for (; j < end4; j += 4) {
            u64 e0 = *(const u64*)(edge16 + j);
            uint4 q0 = *(const uint4*)(Ybase + (size_t)(e0 & 0xffff) * 32 + cl);
            uint4 q1 = *(const uint4*)(Ybase + (size_t)((e0 >> 16) & 0xffff) * 32 + cl);
            uint4 q2 = *(const uint4*)(Ybase + (size_t)((e0 >> 32) & 0xffff) * 32 + cl);
            uint4 q3 = *(const uint4*)(Ybase + (size_t)(e0 >> 48) * 32 + cl);
#pragma unroll
            for (int k = 0; k < 4; ++k) {
                uint4 q = k==0?q0:k==1?q1:k==2?q2:q3;
                a[0] += __uint_as_float(q.x << 16);
                a[1] += __uint_as_float(q.x & 0xffff0000u);
                a[2] += __uint_as_float(q.y << 16);
                a[3] += __uint_as_float(q.y & 0xffff0000u);
                a[4] += __uint_as_float(q.z << 16);
                a[5] += __uint_as_float(q.z & 0xffff0000u);
                a[6] += __uint_as_float(q.w << 16);
                a[7] += __uint_as_float(q.w & 0xffff0000u);
            }
        }

        f32x4 r0, r1;
        if (dg > 0) {
            float inv = 1.0f / (float)dg;
#pragma unroll
            for (int i = 0; i < 4; ++i) {
                r0[i] = a[i] * inv + bv0[i];
                r1[i] = a[4 + i] * inv + bv1[i];
            }
        } else {
            uint4 q = *(const uint4*)(Ybase + (size_t)node * 32 + cl);
            u32 w[4] = {q.x, q.y, q.z, q.w};
#pragma unroll
            for (int i = 0; i < 4; ++i) {
                float lo = __uint_as_float(w[i] << 16);
                float hi = __uint_as_float(w[i] & 0xffff0000u);
                if (i < 2) { r0[2*i] = lo + bv0[2*i]; r0[2*i+1] = hi + bv0[2*i+1]; }
                else { r1[2*(i-2)] = lo + bv1[2*(i-2)]; r1[2*(i-2)+1] = hi + bv1[2*(i-2)+1]; }
            }
        }
        // segment (4 lanes) writes 128B contiguous f32
        float* op = out + (size_t)node * DIM + chunk * 32 + cl;
        *(f32x4*)op = r0;
        *(f32x4*)(op + 4) = r1;
    }
}

static inline size_t align64(size_t x) { return (x + 63) & ~(size_t)63; }

extern "C" void kernel_launch(void* const* d_in, const int* in_sizes, int n_in,
                              void* d_out, int out_size, void* d_ws, size_t ws_size,
                              hipStream_t stream) {
    const float* feature = (const float*)d_in[0];
    const int*   src     = (const int*)d_in[1];
    const int*   dst     = (const int*)d_in[2];
    const float* W       = (const float*)d_in[3];
    const float* b       = (const float*)d_in[4];
    float* out = (float*)d_out;

    // workspace layout (~38.2 MB total)
    char* ws = (char*)d_ws;
    __bf16* Yc  = (__bf16*)ws;               ws += align64((size_t)NCHUNK * NPAD * 32 * 2);
    __bf16* Wbf = (__bf16*)ws;               ws += align64((size_t)DIM * DIM * 2);
    int* offs     = (int*)ws;                ws += align64((size_t)N_NODES * 4);
    u16* deg16    = (u16*)ws;                ws += align64((size_t)N_NODES * 2);
    int* bcur     = (int*)ws;                ws += align64((size_t)NBUK * 4);
    unsigned int* staged = (unsigned int*)ws; ws += align64((size_t)NBUK * CAP * 4);
    u16* edge16   = (u16*)ws;                ws += align64((size_t)NBUK * CAP * 2);

    setup_k<<<(DIM * DIM) / 256, 256, 0, stream>>>(W, Wbf, bcur, Yc);
    fused_k<<<GEMM_BLKS + NBLK, 256, 0, stream>>>(feature, Wbf, Yc, src, dst, bcur, staged);
    finalize_k<<<NBUK, 256, 0, stream>>>(staged, bcur, offs, deg16, edge16);
    aggregate_k<<<NCHUNK * AGG_BPC, 256, 0, stream>>>(Yc, offs, deg16, edge16, b, out);
}

// Round 12
// 147.384 us; speedup vs baseline: 2.9408x; 1.0500x over previous
//
#include <hip/hip_runtime.h>
#include <hip/hip_bf16.h>

#define N_NODES 50000
#define NPAD 50016          // Yc row stride: N_NODES padded; rows >= N_NODES are zero
#define DUMMY 50000         // dummy src index -> zero row (padding contributes 0)
#define DIM 256
#define N_EDGES 1600000
#define NBUK 196            // buckets of 256 nodes: 196*256 = 50176 >= 50000
#define CAP 10240           // fixed bucket region capacity (padded mean 9187 + 10 sigma)
#define CHUNK_E 4096        // edges per binning block
#define NBLK ((N_EDGES + CHUNK_E - 1) / CHUNK_E)   // 391
#define GEMM_BLKS ((N_NODES + 63) / 64)            // 782
#define NCHUNK 8            // Y column chunks (32 cols each), one per XCD
#define AGG_BPC 782         // aggregate blocks per chunk: 782*4 warps >= 3125 groups
#define NGROUP (N_NODES / 16)  // 3125 groups of 16 nodes
#define LROW 72             // LDS W-tile row stride in bf16 (144 B, not 0 mod 128B)

typedef float f32x4 __attribute__((ext_vector_type(4)));
typedef __bf16 bf16x8 __attribute__((ext_vector_type(8)));
typedef __bf16 bf16x4 __attribute__((ext_vector_type(4)));
typedef unsigned long long u64;
typedef unsigned int u32;
typedef unsigned short u16;

// ---------------- setup: W -> bf16, init bucket cursors, zero dummy Y rows -----
__global__ __launch_bounds__(256) void setup_k(const float* __restrict__ W,
                                               __bf16* __restrict__ Wbf,
                                               int* __restrict__ bcur,
                                               __bf16* __restrict__ Yc) {
    int i = blockIdx.x * 256 + threadIdx.x;   // grid = 256 blocks: i in [0, 65536)
    Wbf[i] = (__bf16)W[i];
    if (i < NBUK) bcur[i] = i * CAP;
    if (i < NCHUNK * (NPAD - N_NODES) * 32) {  // zero the 16 pad rows per chunk
        int c = i >> 9;            // 16*32 = 512 elems per chunk
        int rem = i & 511;
        Yc[(size_t)c * NPAD * 32 + (size_t)(N_NODES + (rem >> 5)) * 32 + (rem & 31)] = (__bf16)0.0f;
    }
}

// ---------------- fused: gemm role (blocks < GEMM_BLKS) | place role ----------
__global__ __launch_bounds__(256) void fused_k(const float* __restrict__ feat,
                                               const __bf16* __restrict__ Wbf,
                                               __bf16* __restrict__ Yc,
                                               const int* __restrict__ src,
                                               const int* __restrict__ dst,
                                               int* __restrict__ bcur,
                                               unsigned int* __restrict__ staged) {
    __shared__ __bf16 lw[256 * LROW];    // 36 KB W K-quarter tile
    __shared__ int lh[NBUK];
    __shared__ int lbase[NBUK];

    if (blockIdx.x < GEMM_BLKS) {
        // ---- GEMM role ----
        const int wid  = threadIdx.x >> 6;
        const int lane = threadIdx.x & 63;
        const int row0 = blockIdx.x * 64 + wid * 16;
        const int mrow = lane & 15;
        const int kgrp = lane >> 4;          // 0..3

        int arow = row0 + mrow;
        int arow_c = arow < N_NODES ? arow : (N_NODES - 1);
        const float* aptr = feat + (size_t)arow_c * DIM + kgrp * 8;

        const int t = threadIdx.x;
        const int srow = t >> 3;             // base row (stride 32 per iter)
        const int scb  = (t & 7) * 8;        // bf16 col offset within quarter

        f32x4 acc[16];
#pragma unroll
        for (int i = 0; i < 16; ++i) acc[i] = (f32x4)0.0f;

        for (int p = 0; p < 4; ++p) {
            f32x4 ar0 = *(const f32x4*)(aptr + (p * 2) * 32);
            f32x4 ar1 = *(const f32x4*)(aptr + (p * 2) * 32 + 4);
            f32x4 ar2 = *(const f32x4*)(aptr + (p * 2 + 1) * 32);
            f32x4 ar3 = *(const f32x4*)(aptr + (p * 2 + 1) * 32 + 4);

            if (p) __syncthreads();
#pragma unroll
            for (int i = 0; i < 8; ++i) {
                int row = srow + i * 32;
                uint4 v = *(const uint4*)(Wbf + (size_t)row * DIM + p * 64 + scb);
                *(uint4*)(lw + row * LROW + scb) = v;
            }
            __syncthreads();

            bf16x8 af0, af1;
            af0[0] = (__bf16)ar0[0]; af0[1] = (__bf16)ar0[1];
            af0[2] = (__bf16)ar0[2]; af0[3] = (__bf16)ar0[3];
            af0[4] = (__bf16)ar1[0]; af0[5] = (__bf16)ar1[1];
            af0[6] = (__bf16)ar1[2]; af0[7] = (__bf16)ar1[3];
            af1[0] = (__bf16)ar2[0]; af1[1] = (__bf16)ar2[1];
            af1[2] = (__bf16)ar2[2]; af1[3] = (__bf16)ar2[3];
            af1[4] = (__bf16)ar3[0]; af1[5] = (__bf16)ar3[1];
            af1[6] = (__bf16)ar3[2]; af1[7] = (__bf16)ar3[3];

#pragma unroll
            for (int nt = 0; nt < 16; ++nt) {
                const __bf16* lp = lw + (nt * 16 + mrow) * LROW + kgrp * 8;
                bf16x8 wf0 = *(const bf16x8*)(lp);
                bf16x8 wf1 = *(const bf16x8*)(lp + 32);
                acc[nt] = __builtin_amdgcn_mfma_f32_16x16x32_bf16(wf0, af0, acc[nt], 0, 0, 0);
                acc[nt] = __builtin_amdgcn_mfma_f32_16x16x32_bf16(wf1, af1, acc[nt], 0, 0, 0);
            }
        }

        const int node = row0 + mrow;
        if (node < N_NODES) {
#pragma unroll
            for (int nt = 0; nt < 16; ++nt) {
                int oc0 = nt * 16 + kgrp * 4;
                bf16x4 pv;
                pv[0] = (__bf16)acc[nt][0];
                pv[1] = (__bf16)acc[nt][1];
                pv[2] = (__bf16)acc[nt][2];
                pv[3] = (__bf16)acc[nt][3];
                __bf16* yp = Yc + (size_t)(oc0 >> 5) * NPAD * 32
                                + (size_t)node * 32 + (oc0 & 31);
                *(bf16x4*)yp = pv;
            }
        }
    } else {
        // ---- place role ----
        int pb = blockIdx.x - GEMM_BLKS;     // 0..NBLK-1
        for (int i = threadIdx.x; i < NBUK; i += 256) lh[i] = 0;
        __syncthreads();
        int base = pb * CHUNK_E;
        int end = base + CHUNK_E; if (end > N_EDGES) end = N_EDGES;
        for (int e = base + threadIdx.x; e < end; e += 256)
            atomicAdd(&lh[dst[e] >> 8], 1);
        __syncthreads();
        for (int i = threadIdx.x; i < NBUK; i += 256) {
            int c = lh[i];
            lbase[i] = c ? atomicAdd(&bcur[i], c) : 0;
            lh[i] = 0;                 // reuse as local cursor
        }
        __syncthreads();
        for (int e = base + threadIdx.x; e < end; e += 256) {
            int d = dst[e];
            int s = src[e];            // < 50000 -> fits in 16 bits
            int b = d >> 8;
            int p = atomicAdd(&lh[b], 1);
            staged[lbase[b] + p] = (unsigned int)s | ((unsigned int)(d & 255) << 16);
        }
    }
}

// ---------------- per-bucket finalize: node offsets/degrees + u16 edge lists ----
// Per-node lists padded to a multiple of 8 with DUMMY (zero-row) indices:
// aggregate reads aligned u64 (4 edges) in uniform 8-edge batches, no remainder.
__global__ __launch_bounds__(256) void finalize_k(const unsigned int* __restrict__ staged,
                                                  const int* __restrict__ bcur,
                                                  int* __restrict__ offs,
                                                  u16* __restrict__ deg16,
                                                  u16* __restrict__ edge16) {
    __shared__ int nh[256];
    __shared__ int nbase[256];
    __shared__ int sm[256];
    int t = threadIdx.x, b = blockIdx.x;
    int beg = b * CAP;
    int cnt = bcur[b] - beg;
    nh[t] = 0;
    __syncthreads();
    for (int i = t; i < cnt; i += 256)
        atomicAdd(&nh[staged[beg + i] >> 16], 1);
    __syncthreads();
    int v = nh[t];
    int v8 = (v + 7) & ~7;         // padded count (multiple of 8)
    sm[t] = v8;
    __syncthreads();
    for (int off = 1; off < 256; off <<= 1) {
        int x = (t >= off) ? sm[t - off] : 0;
        __syncthreads();
        sm[t] += x;
        __syncthreads();
    }
    nbase[t] = sm[t] - v8;         // exclusive prefix of padded counts (8-aligned)
    int node = (b << 8) + t;
    if (node < N_NODES) {
        offs[node]  = beg + nbase[t];
        deg16[node] = (u16)v;
    }
    // fill the pad slots with DUMMY
    for (int i = v; i < v8; ++i)
        edge16[beg + nbase[t] + i] = (u16)DUMMY;
    nh[t] = 0;                     // reuse as per-node cursor
    __syncthreads();
    for (int i = t; i < cnt; i += 256) {
        unsigned int u = staged[beg + i];
        int dl = (int)(u >> 16);
        int p = atomicAdd(&nh[dl], 1);
        edge16[beg + nbase[dl] + p] = (u16)(u & 0xFFFFu);
    }
}

// ---------------- per-node gather-mean + bias, column-chunked, pipelined -------
// chunk = blockIdx & 7 (XCD round-robin); per-XCD working set = 3.2MB (L2-resident)
// wave = 16 nodes; segment (4 lanes) owns one node; lane covers 8 cols (16B/edge).
// 8-edge batches; NEXT batch's edge words prefetched during current gathers+ACC
// so gather addresses are always ready (breaks the edge-load -> gather chain).
// hi-bf16 accumulated from raw u32 (low mantissa garbage <= 2^-8 rel, random sign).
#define GQ(ev) (*(const uint4*)(Ybase + (size_t)((u32)(ev) & 0xffffu) * 32 + cl))
#define ACCQ(q) do { \
    a0 += __uint_as_float((q).x << 16); a1 += __uint_as_float((q).x); \
    a2 += __uint_as_float((q).y << 16); a3 += __uint_as_float((q).y); \
    a4 += __uint_as_float((q).z << 16); a5 += __uint_as_float((q).z); \
    a6 += __uint_as_float((q).w << 16); a7 += __uint_as_float((q).w); \
} while (0)

__global__ __launch_bounds__(256) void aggregate_k(const __bf16* __restrict__ Yc,
                                                   const int* __restrict__ offs,
                                                   const u16* __restrict__ deg16,
                                                   const u16* __restrict__ edge16,
                                                   const float* __restrict__ bias,
                                                   float* __restrict__ out) {
    const int chunk = blockIdx.x & 7;
    const int bic   = blockIdx.x >> 3;      // block index within chunk
    const int wid   = threadIdx.x >> 6;
    const int lane  = threadIdx.x & 63;
    const int seg   = lane >> 2;            // node slot 0..15
    const int cl    = (lane & 3) * 8;       // bf16 col within chunk: 0,8,16,24

    const int g = bic * 4 + wid;            // one group per warp
    if (g >= NGROUP) return;
    const int node = g * 16 + seg;

    const __bf16* Ybase = Yc + (size_t)chunk * NPAD * 32;
    const float* bp = bias + chunk * 32 + cl;
    const f32x4 bv0 = *(const f32x4*)bp;
    const f32x4 bv1 = *(const f32x4*)(bp + 4);

    const int beg = offs[node];
    const int dg  = (int)deg16[node];

    float a0 = 0.f, a1 = 0.f, a2 = 0.f, a3 = 0.f;
    float a4 = 0.f, a5 = 0.f, a6 = 0.f, a7 = 0.f;

    f32x4 r0, r1;
    if (dg > 0) {
        const int end8 = beg + ((dg + 7) & ~7);
        int j = beg;
        u64 eA = *(const u64*)(edge16 + j);
        u64 eB = *(const u64*)(edge16 + j + 4);
        while (1) {
            // prefetch next batch's edge words (may read past list: loaded, unused)
            u64 eC = *(const u64*)(edge16 + j + 8);
            u64 eD = *(const u64*)(edge16 + j + 12);
            uint4 q0 = GQ(eA);
            uint4 q1 = GQ(eA >> 16);
            uint4 q2 = GQ(eA >> 32);
            uint4 q3 = GQ(eA >> 48);
            uint4 q4 = GQ(eB);
            uint4 q5 = GQ(eB >> 16);
            uint4 q6 = GQ(eB >> 32);
            uint4 q7 = GQ(eB >> 48);
            ACCQ(q0); ACCQ(q1); ACCQ(q2); ACCQ(q3);
            ACCQ(q4); ACCQ(q5); ACCQ(q6); ACCQ(q7);
            j += 8;
            if (j >= end8) break;
            eA = eC; eB = eD;
        }
        float inv = 1.0f / (float)dg;
        r0[0] = a0 * inv + bv0[0];
        r0[1] = a1 * inv + bv0[1];
        r0[2] = a2 * inv + bv0[2];
        r0[3] = a3 * inv + bv0[3];
        r1[0] = a4 * inv + bv1[0];
        r1[1] = a5 * inv + bv1[1];
        r1[2] = a6 * inv + bv1[2];
        r1[3] = a7 * inv + bv1[3];
    } else {
        uint4 q = *(const uint4*)(Ybase + (size_t)node * 32 + cl);
        r0[0] = __uint_as_float(q.x << 16) + bv0[0];
        r0[1] = __uint_as_float(q.x & 0xffff0000u) + bv0[1];
        r0[2] = __uint_as_float(q.y << 16) + bv0[2];
        r0[3] = __uint_as_float(q.y & 0xffff0000u) + bv0[3];
        r1[0] = __uint_as_float(q.z << 16) + bv1[0];
        r1[1] = __uint_as_float(q.z & 0xffff0000u) + bv1[1];
        r1[2] = __uint_as_float(q.w << 16) + bv1[2];
        r1[3] = __uint_as_float(q.w & 0xffff0000u) + bv1[3];
    }
    // segment (4 lanes) writes 128B contiguous f32
    float* op = out + (size_t)node * DIM + chunk * 32 + cl;
    *(f32x4*)op = r0;
    *(f32x4*)(op + 4) = r1;
}

static inline size_t align64(size_t x) { return (x + 63) & ~(size_t)63; }

extern "C" void kernel_launch(void* const* d_in, const int* in_sizes, int n_in,
                              void* d_out, int out_size, void* d_ws, size_t ws_size,
                              hipStream_t stream) {
    const float* feature = (const float*)d_in[0];
    const int*   src     = (const int*)d_in[1];
    const int*   dst     = (const int*)d_in[2];
    const float* W       = (const float*)d_in[3];
    const float* b       = (const float*)d_in[4];
    float* out = (float*)d_out;

    // workspace layout (~38.2 MB total)
    char* ws = (char*)d_ws;
    __bf16* Yc  = (__bf16*)ws;               ws += align64((size_t)NCHUNK * NPAD * 32 * 2);
    __bf16* Wbf = (__bf16*)ws;               ws += align64((size_t)DIM * DIM * 2);
    int* offs     = (int*)ws;                ws += align64((size_t)N_NODES * 4);
    u16* deg16    = (u16*)ws;                ws += align64((size_t)N_NODES * 2);
    int* bcur     = (int*)ws;                ws += align64((size_t)NBUK * 4);
    unsigned int* staged = (unsigned int*)ws; ws += align64((size_t)NBUK * CAP * 4);
    u16* edge16   = (u16*)ws;                ws += align64((size_t)NBUK * CAP * 2 + 64);

    setup_k<<<(DIM * DIM) / 256, 256, 0, stream>>>(W, Wbf, bcur, Yc);
    fused_k<<<GEMM_BLKS + NBLK, 256, 0, stream>>>(feature, Wbf, Yc, src, dst, bcur, staged);
    finalize_k<<<NBUK, 256, 0, stream>>>(staged, bcur, offs, deg16, edge16);
    aggregate_k<<<NCHUNK * AGG_BPC, 256, 0, stream>>>(Yc, offs, deg16, edge16, b, out);
}

// Round 13
// 143.156 us; speedup vs baseline: 3.0276x; 1.0295x over previous
//
#include <hip/hip_runtime.h>
#include <hip/hip_bf16.h>

#define N_NODES 50000
#define NPAD 50016          // Yc row stride: N_NODES padded; rows >= N_NODES are zero
#define DUMMY 50000         // dummy src index -> zero row (padding contributes 0)
#define DIM 256
#define N_EDGES 1600000
#define NBUK 196            // buckets of 256 nodes: 196*256 = 50176 >= 50000
#define CAP 10240           // fixed bucket region capacity (8-padded mean 9190 + 11 sigma)
#define CHUNK_E 4096        // edges per binning block
#define NBLK ((N_EDGES + CHUNK_E - 1) / CHUNK_E)   // 391
#define GEMM_BLKS ((N_NODES + 63) / 64)            // 782
#define NCHUNK 8            // Y column chunks (32 cols each), one per XCD
#define AGG_BPC 782         // aggregate blocks per chunk: 782*4 warps >= 3125 groups
#define NGROUP (N_NODES / 16)  // 3125 groups of 16 nodes
#define LROW 72             // LDS W-tile row stride in bf16 (144 B, not 0 mod 128B)

typedef float f32x4 __attribute__((ext_vector_type(4)));
typedef __bf16 bf16x8 __attribute__((ext_vector_type(8)));
typedef __bf16 bf16x4 __attribute__((ext_vector_type(4)));
typedef unsigned long long u64;
typedef unsigned int u32;
typedef unsigned short u16;

// ---------------- setup: W -> bf16, init bucket cursors, zero dummy Y rows -----
__global__ __launch_bounds__(256) void setup_k(const float* __restrict__ W,
                                               __bf16* __restrict__ Wbf,
                                               int* __restrict__ bcur,
                                               __bf16* __restrict__ Yc) {
    int i = blockIdx.x * 256 + threadIdx.x;   // grid = 256 blocks: i in [0, 65536)
    Wbf[i] = (__bf16)W[i];
    if (i < NBUK) bcur[i] = i * CAP;
    if (i < NCHUNK * (NPAD - N_NODES) * 32) {  // zero the 16 pad rows per chunk
        int c = i >> 9;            // 16*32 = 512 elems per chunk
        int rem = i & 511;
        Yc[(size_t)c * NPAD * 32 + (size_t)(N_NODES + (rem >> 5)) * 32 + (rem & 31)] = (__bf16)0.0f;
    }
}

// ---------------- fused: gemm role (blocks < GEMM_BLKS) | place role ----------
__global__ __launch_bounds__(256) void fused_k(const float* __restrict__ feat,
                                               const __bf16* __restrict__ Wbf,
                                               __bf16* __restrict__ Yc,
                                               const int* __restrict__ src,
                                               const int* __restrict__ dst,
                                               int* __restrict__ bcur,
                                               unsigned int* __restrict__ staged) {
    __shared__ __bf16 lw[256 * LROW];    // 36 KB W K-quarter tile
    __shared__ int lh[NBUK];
    __shared__ int lbase[NBUK];

    if (blockIdx.x < GEMM_BLKS) {
        // ---- GEMM role ----
        const int wid  = threadIdx.x >> 6;
        const int lane = threadIdx.x & 63;
        const int row0 = blockIdx.x * 64 + wid * 16;
        const int mrow = lane & 15;
        const int kgrp = lane >> 4;          // 0..3

        int arow = row0 + mrow;
        int arow_c = arow < N_NODES ? arow : (N_NODES - 1);
        const float* aptr = feat + (size_t)arow_c * DIM + kgrp * 8;

        const int t = threadIdx.x;
        const int srow = t >> 3;             // base row (stride 32 per iter)
        const int scb  = (t & 7) * 8;        // bf16 col offset within quarter

        f32x4 acc[16];
#pragma unroll
        for (int i = 0; i < 16; ++i) acc[i] = (f32x4)0.0f;

        for (int p = 0; p < 4; ++p) {
            f32x4 ar0 = *(const f32x4*)(aptr + (p * 2) * 32);
            f32x4 ar1 = *(const f32x4*)(aptr + (p * 2) * 32 + 4);
            f32x4 ar2 = *(const f32x4*)(aptr + (p * 2 + 1) * 32);
            f32x4 ar3 = *(const f32x4*)(aptr + (p * 2 + 1) * 32 + 4);

            if (p) __syncthreads();
#pragma unroll
            for (int i = 0; i < 8; ++i) {
                int row = srow + i * 32;
                uint4 v = *(const uint4*)(Wbf + (size_t)row * DIM + p * 64 + scb);
                *(uint4*)(lw + row * LROW + scb) = v;
            }
            __syncthreads();

            bf16x8 af0, af1;
            af0[0] = (__bf16)ar0[0]; af0[1] = (__bf16)ar0[1];
            af0[2] = (__bf16)ar0[2]; af0[3] = (__bf16)ar0[3];
            af0[4] = (__bf16)ar1[0]; af0[5] = (__bf16)ar1[1];
            af0[6] = (__bf16)ar1[2]; af0[7] = (__bf16)ar1[3];
            af1[0] = (__bf16)ar2[0]; af1[1] = (__bf16)ar2[1];
            af1[2] = (__bf16)ar2[2]; af1[3] = (__bf16)ar2[3];
            af1[4] = (__bf16)ar3[0]; af1[5] = (__bf16)ar3[1];
            af1[6] = (__bf16)ar3[2]; af1[7] = (__bf16)ar3[3];

#pragma unroll
            for (int nt = 0; nt < 16; ++nt) {
                const __bf16* lp = lw + (nt * 16 + mrow) * LROW + kgrp * 8;
                bf16x8 wf0 = *(const bf16x8*)(lp);
                bf16x8 wf1 = *(const bf16x8*)(lp + 32);
                acc[nt] = __builtin_amdgcn_mfma_f32_16x16x32_bf16(wf0, af0, acc[nt], 0, 0, 0);
                acc[nt] = __builtin_amdgcn_mfma_f32_16x16x32_bf16(wf1, af1, acc[nt], 0, 0, 0);
            }
        }

        const int node = row0 + mrow;
        if (node < N_NODES) {
#pragma unroll
            for (int nt = 0; nt < 16; ++nt) {
                int oc0 = nt * 16 + kgrp * 4;
                bf16x4 pv;
                pv[0] = (__bf16)acc[nt][0];
                pv[1] = (__bf16)acc[nt][1];
                pv[2] = (__bf16)acc[nt][2];
                pv[3] = (__bf16)acc[nt][3];
                __bf16* yp = Yc + (size_t)(oc0 >> 5) * NPAD * 32
                                + (size_t)node * 32 + (oc0 & 31);
                *(bf16x4*)yp = pv;
            }
        }
    } else {
        // ---- place role ----
        int pb = blockIdx.x - GEMM_BLKS;     // 0..NBLK-1
        for (int i = threadIdx.x; i < NBUK; i += 256) lh[i] = 0;
        __syncthreads();
        int base = pb * CHUNK_E;
        int end = base + CHUNK_E; if (end > N_EDGES) end = N_EDGES;
        for (int e = base + threadIdx.x; e < end; e += 256)
            atomicAdd(&lh[dst[e] >> 8], 1);
        __syncthreads();
        for (int i = threadIdx.x; i < NBUK; i += 256) {
            int c = lh[i];
            lbase[i] = c ? atomicAdd(&bcur[i], c) : 0;
            lh[i] = 0;                 // reuse as local cursor
        }
        __syncthreads();
        for (int e = base + threadIdx.x; e < end; e += 256) {
            int d = dst[e];
            int s = src[e];            // < 50000 -> fits in 16 bits
            int b = d >> 8;
            int p = atomicAdd(&lh[b], 1);
            staged[lbase[b] + p] = (unsigned int)s | ((unsigned int)(d & 255) << 16);
        }
    }
}

// ---------------- per-bucket finalize: node offsets/degrees + u16 edge lists ----
// Per-node lists padded to a multiple of 8 with DUMMY (zero-row) indices.
__global__ __launch_bounds__(256) void finalize_k(const unsigned int* __restrict__ staged,
                                                  const int* __restrict__ bcur,
                                                  int* __restrict__ offs,
                                                  u16* __restrict__ deg16,
                                                  u16* __restrict__ edge16) {
    __shared__ int nh[256];
    __shared__ int nbase[256];
    __shared__ int sm[256];
    int t = threadIdx.x, b = blockIdx.x;
    int beg = b * CAP;
    int cnt = bcur[b] - beg;
    nh[t] = 0;
    __syncthreads();
    for (int i = t; i < cnt; i += 256)
        atomicAdd(&nh[staged[beg + i] >> 16], 1);
    __syncthreads();
    int v = nh[t];
    int v8 = (v + 7) & ~7;         // padded count (multiple of 8)
    sm[t] = v8;
    __syncthreads();
    for (int off = 1; off < 256; off <<= 1) {
        int x = (t >= off) ? sm[t - off] : 0;
        __syncthreads();
        sm[t] += x;
        __syncthreads();
    }
    nbase[t] = sm[t] - v8;         // exclusive prefix of padded counts (8-aligned)
    int node = (b << 8) + t;
    if (node < N_NODES) {
        offs[node]  = beg + nbase[t];
        deg16[node] = (u16)v;
    }
    // fill the pad slots with DUMMY
    for (int i = v; i < v8; ++i)
        edge16[beg + nbase[t] + i] = (u16)DUMMY;
    nh[t] = 0;                     // reuse as per-node cursor
    __syncthreads();
    for (int i = t; i < cnt; i += 256) {
        unsigned int u = staged[beg + i];
        int dl = (int)(u >> 16);
        int p = atomicAdd(&nh[dl], 1);
        edge16[beg + nbase[dl] + p] = (u16)(u & 0xFFFFu);
    }
}

// ---------------- per-node gather-mean + bias, column-chunked, 16-deep pipeline -
// chunk = blockIdx & 7 (XCD round-robin); per-XCD working set = 3.2MB (L2-resident)
// wave = 16 nodes; segment (4 lanes) owns one node; lane covers 8 cols (16B/edge).
// TWO 8-edge batches per iteration: 16 independent gathers + 4 edge-word
// prefetches in flight before the first accumulate (2x R12's pipeline depth).
#define GQ(ev) (*(const uint4*)(Ybase + (size_t)((u32)(ev) & 0xffffu) * 32 + cl))
#define ACCQ(q) do { \
    a0 += __uint_as_float((q).x << 16); a1 += __uint_as_float((q).x); \
    a2 += __uint_as_float((q).y << 16); a3 += __uint_as_float((q).y); \
    a4 += __uint_as_float((q).z << 16); a5 += __uint_as_float((q).z); \
    a6 += __uint_as_float((q).w << 16); a7 += __uint_as_float((q).w); \
} while (0)

__global__ __launch_bounds__(256) void aggregate_k(const __bf16* __restrict__ Yc,
                                                   const int* __restrict__ offs,
                                                   const u16* __restrict__ deg16,
                                                   const u16* __restrict__ edge16,
                                                   const float* __restrict__ bias,
                                                   float* __restrict__ out) {
    const int chunk = blockIdx.x & 7;
    const int bic   = blockIdx.x >> 3;      // block index within chunk
    const int wid   = threadIdx.x >> 6;
    const int lane  = threadIdx.x & 63;
    const int seg   = lane >> 2;            // node slot 0..15
    const int cl    = (lane & 3) * 8;       // bf16 col within chunk: 0,8,16,24

    const int g = bic * 4 + wid;            // one group per warp
    if (g >= NGROUP) return;
    const int node = g * 16 + seg;

    const __bf16* Ybase = Yc + (size_t)chunk * NPAD * 32;
    const float* bp = bias + chunk * 32 + cl;
    const f32x4 bv0 = *(const f32x4*)bp;
    const f32x4 bv1 = *(const f32x4*)(bp + 4);

    const int beg = offs[node];
    const int dg  = (int)deg16[node];

    float a0 = 0.f, a1 = 0.f, a2 = 0.f, a3 = 0.f;
    float a4 = 0.f, a5 = 0.f, a6 = 0.f, a7 = 0.f;

    f32x4 r0, r1;
    if (dg > 0) {
        const int nb8 = (dg + 7) >> 3;      // number of 8-edge batches
        const int npair = nb8 >> 1;
        const int odd = nb8 & 1;
        int j = beg;
        // first pair's edge words (second half may be beyond-list: in-bucket/slack)
        u64 eA = *(const u64*)(edge16 + j);
        u64 eB = *(const u64*)(edge16 + j + 4);
        u64 eC = *(const u64*)(edge16 + j + 8);
        u64 eD = *(const u64*)(edge16 + j + 12);
        for (int p = 0; p < npair; ++p) {
            // prefetch next pair's edge words
            u64 nA = *(const u64*)(edge16 + j + 16);
            u64 nB = *(const u64*)(edge16 + j + 20);
            u64 nC = *(const u64*)(edge16 + j + 24);
            u64 nD = *(const u64*)(edge16 + j + 28);
            // 16 independent gathers in flight
            uint4 q0 = GQ(eA);       uint4 q1 = GQ(eA >> 16);
            uint4 q2 = GQ(eA >> 32); uint4 q3 = GQ(eA >> 48);
            uint4 q4 = GQ(eB);       uint4 q5 = GQ(eB >> 16);
            uint4 q6 = GQ(eB >> 32); uint4 q7 = GQ(eB >> 48);
            uint4 q8 = GQ(eC);       uint4 q9 = GQ(eC >> 16);
            uint4 qa = GQ(eC >> 32); uint4 qb = GQ(eC >> 48);
            uint4 qc = GQ(eD);       uint4 qd = GQ(eD >> 16);
            uint4 qe = GQ(eD >> 32); uint4 qf = GQ(eD >> 48);
            ACCQ(q0); ACCQ(q1); ACCQ(q2); ACCQ(q3);
            ACCQ(q4); ACCQ(q5); ACCQ(q6); ACCQ(q7);
            ACCQ(q8); ACCQ(q9); ACCQ(qa); ACCQ(qb);
            ACCQ(qc); ACCQ(qd); ACCQ(qe); ACCQ(qf);
            j += 16;
            eA = nA; eB = nB; eC = nC; eD = nD;
        }
        if (odd) {
            // last lone batch: words already in eA, eB
            uint4 q0 = GQ(eA);       uint4 q1 = GQ(eA >> 16);
            uint4 q2 = GQ(eA >> 32); uint4 q3 = GQ(eA >> 48);
            uint4 q4 = GQ(eB);       uint4 q5 = GQ(eB >> 16);
            uint4 q6 = GQ(eB >> 32); uint4 q7 = GQ(eB >> 48);
            ACCQ(q0); ACCQ(q1); ACCQ(q2); ACCQ(q3);
            ACCQ(q4); ACCQ(q5); ACCQ(q6); ACCQ(q7);
        }
        float inv = 1.0f / (float)dg;
        r0[0] = a0 * inv + bv0[0];
        r0[1] = a1 * inv + bv0[1];
        r0[2] = a2 * inv + bv0[2];
        r0[3] = a3 * inv + bv0[3];
        r1[0] = a4 * inv + bv1[0];
        r1[1] = a5 * inv + bv1[1];
        r1[2] = a6 * inv + bv1[2];
        r1[3] = a7 * inv + bv1[3];
    } else {
        uint4 q = *(const uint4*)(Ybase + (size_t)node * 32 + cl);
        r0[0] = __uint_as_float(q.x << 16) + bv0[0];
        r0[1] = __uint_as_float(q.x & 0xffff0000u) + bv0[1];
        r0[2] = __uint_as_float(q.y << 16) + bv0[2];
        r0[3] = __uint_as_float(q.y & 0xffff0000u) + bv0[3];
        r1[0] = __uint_as_float(q.z << 16) + bv1[0];
        r1[1] = __uint_as_float(q.z & 0xffff0000u) + bv1[1];
        r1[2] = __uint_as_float(q.w << 16) + bv1[2];
        r1[3] = __uint_as_float(q.w & 0xffff0000u) + bv1[3];
    }
    // segment (4 lanes) writes 128B contiguous f32
    float* op = out + (size_t)node * DIM + chunk * 32 + cl;
    *(f32x4*)op = r0;
    *(f32x4*)(op + 4) = r1;
}

static inline size_t align64(size_t x) { return (x + 63) & ~(size_t)63; }

extern "C" void kernel_launch(void* const* d_in, const int* in_sizes, int n_in,
                              void* d_out, int out_size, void* d_ws, size_t ws_size,
                              hipStream_t stream) {
    const float* feature = (const float*)d_in[0];
    const int*   src     = (const int*)d_in[1];
    const int*   dst     = (const int*)d_in[2];
    const float* W       = (const float*)d_in[3];
    const float* b       = (const float*)d_in[4];
    float* out = (float*)d_out;

    // workspace layout (~38.2 MB total)
    char* ws = (char*)d_ws;
    __bf16* Yc  = (__bf16*)ws;               ws += align64((size_t)NCHUNK * NPAD * 32 * 2);
    __bf16* Wbf = (__bf16*)ws;               ws += align64((size_t)DIM * DIM * 2);
    int* offs     = (int*)ws;                ws += align64((size_t)N_NODES * 4);
    u16* deg16    = (u16*)ws;                ws += align64((size_t)N_NODES * 2);
    int* bcur     = (int*)ws;                ws += align64((size_t)NBUK * 4);
    unsigned int* staged = (unsigned int*)ws; ws += align64((size_t)NBUK * CAP * 4);
    u16* edge16   = (u16*)ws;                ws += align64((size_t)NBUK * CAP * 2 + 128);

    setup_k<<<(DIM * DIM) / 256, 256, 0, stream>>>(W, Wbf, bcur, Yc);
    fused_k<<<GEMM_BLKS + NBLK, 256, 0, stream>>>(feature, Wbf, Yc, src, dst, bcur, staged);
    finalize_k<<<NBUK, 256, 0, stream>>>(staged, bcur, offs, deg16, edge16);
    aggregate_k<<<NCHUNK * AGG_BPC, 256, 0, stream>>>(Yc, offs, deg16, edge16, b, out);
}